// Round 8
// baseline (289.436 us; speedup 1.0000x reference)
//
#include <hip/hip_runtime.h>

#define N_NODES 20000
#define E_EDGES 160000
#define IN_CH 128
#define H_HEADS 8
#define C_CH 64
#define HC 512
#define M_TOT (E_EDGES + N_NODES)
#define NEG_SLOPE 0.2f
#define NCHUNK ((N_NODES + 255) / 256)

typedef __attribute__((ext_vector_type(8))) short bf16x8;
typedef __attribute__((ext_vector_type(4))) float f32x4;

__device__ __forceinline__ unsigned short f2bf(float f) {
    unsigned u = __float_as_uint(f);
    unsigned r = (u + 0x7FFFu + ((u >> 16) & 1u)) >> 16;   // RNE
    return (unsigned short)r;
}
__device__ __forceinline__ unsigned short f2bf_trunc(float f) {
    return (unsigned short)(__float_as_uint(f) >> 16);     // 1-inst truncate (xeT only)
}
__device__ __forceinline__ float bf2f(unsigned short s) {
    return __uint_as_float((unsigned)s << 16);
}
__device__ __forceinline__ float bfx(const bf16x8& v0, const bf16x8& v1, int idx) {
    return bf2f((unsigned short)((idx < 8) ? v0[idx] : v1[idx - 8]));
}

#define GLOAD_LDS16(gsrc, ldst) \
    __builtin_amdgcn_global_load_lds((const __attribute__((address_space(1))) void*)(gsrc), \
                                     (__attribute__((address_space(3))) void*)(ldst), 16, 0, 0)

// ---------------- CSR build ----------------
__global__ void k_deg(const int* __restrict__ ei, int* __restrict__ deg) {
    int e = blockIdx.x * blockDim.x + threadIdx.x;
    if (e >= E_EDGES) return;
    atomicAdd(&deg[ei[E_EDGES + e]], 1);
}

__global__ void k_scan1(const int* __restrict__ deg, int* __restrict__ bsum) {
    __shared__ int red[256];
    int tid = threadIdx.x;
    int i = blockIdx.x * 256 + tid;
    red[tid] = (i < N_NODES) ? deg[i] + 1 : 0;
    __syncthreads();
    for (int off = 128; off > 0; off >>= 1) {
        if (tid < off) red[tid] += red[tid + off];
        __syncthreads();
    }
    if (tid == 0) bsum[blockIdx.x] = red[0];
}

__global__ void k_scan2(const int* __restrict__ bsum, int* __restrict__ boff) {
    if (threadIdx.x == 0) {
        int run = 0;
        for (int b = 0; b < NCHUNK; ++b) { boff[b] = run; run += bsum[b]; }
    }
}

__global__ void k_scan3(const int* __restrict__ deg, const int* __restrict__ boff,
                        int* __restrict__ rowptr, int* __restrict__ cursor,
                        int* __restrict__ eidx, int* __restrict__ src_s,
                        int* __restrict__ dst_s) {
    __shared__ int buf[256];
    int tid = threadIdx.x;
    int i = blockIdx.x * 256 + tid;
    int v = (i < N_NODES) ? deg[i] + 1 : 0;
    buf[tid] = v;
    __syncthreads();
    for (int off = 1; off < 256; off <<= 1) {
        int tv = (tid >= off) ? buf[tid - off] : 0;
        __syncthreads();
        buf[tid] += tv;
        __syncthreads();
    }
    if (i < N_NODES) {
        int excl = boff[blockIdx.x] + buf[tid] - v;
        rowptr[i] = excl;
        eidx[excl] = E_EDGES + i;   // self-loop edge in slot 0
        src_s[excl] = i;
        dst_s[excl] = i;
        cursor[i] = excl + 1;
        if (i == N_NODES - 1) rowptr[N_NODES] = excl + v;   // == M_TOT
    }
}

__global__ void k_fill(const int* __restrict__ ei, int* __restrict__ cursor,
                       int* __restrict__ eidx, int* __restrict__ src_s,
                       int* __restrict__ dst_s) {
    int e = blockIdx.x * blockDim.x + threadIdx.x;
    if (e >= E_EDGES) return;
    int d = ei[E_EDGES + e];
    int slot = atomicAdd(&cursor[d], 1);
    eidx[slot] = e;
    src_s[slot] = ei[e];
    dst_s[slot] = d;
}

// ---------------- k_prep: eab[p][128] bf16 in CSR order + self-loop mean ----------------
// 2 waves per node (64 channels each), 2-deep prefetch.
__global__ void k_prep(const int* __restrict__ rowptr, const int* __restrict__ eidx,
                       const float* __restrict__ ea, unsigned short* __restrict__ eab) {
    int gid = (blockIdx.x * blockDim.x + threadIdx.x) >> 6;
    int node = gid >> 1;
    int half = gid & 1;
    int lane = threadIdx.x & 63;
    if (node >= N_NODES) return;
    int c = half * 64 + lane;
    int beg = rowptr[node] + 1, end = rowptr[node + 1];
    float s = 0.f;
    float v0 = 0.f, v1 = 0.f;
    if (beg < end)     v0 = ea[(size_t)eidx[beg] * 128 + c];
    if (beg + 1 < end) v1 = ea[(size_t)eidx[beg + 1] * 128 + c];
    for (int p = beg; p < end; ++p) {
        float cur = v0;
        v0 = v1;
        if (p + 2 < end) v1 = ea[(size_t)eidx[p + 2] * 128 + c];
        s += cur;
        eab[(size_t)p * 128 + c] = f2bf(cur);
    }
    eab[(size_t)(beg - 1) * 128 + c] = f2bf(s / fmaxf((float)(end - beg), 1.f));
}

// ---------------- weight transpose + bf16 (all three) ----------------
__global__ void k_trans3(const float* __restrict__ Wl, const float* __restrict__ Wr,
                         const float* __restrict__ We,
                         unsigned short* __restrict__ WlT, unsigned short* __restrict__ WrT,
                         unsigned short* __restrict__ WeT) {
    int idx = blockIdx.x * blockDim.x + threadIdx.x;
    if (idx >= HC * IN_CH) return;
    int m = blockIdx.y;
    const float* W = (m == 0) ? Wl : (m == 1) ? Wr : We;
    unsigned short* WT = (m == 0) ? WlT : (m == 1) ? WrT : WeT;
    int n = idx >> 7, k = idx & 127;
    WT[idx] = f2bf(W[(size_t)k * HC + n]);
}

// ---------------- merged dual MFMA GEMM: xlb = bf16(x@Wl), xrb = bf16(x@Wr) ----------------
// grid.y = 2 (sel); both 256-col halves computed per block (x staged once).
__global__ void k_gemm2(const float* __restrict__ A,
                        const unsigned short* __restrict__ WlT,
                        const unsigned short* __restrict__ WrT,
                        unsigned short* __restrict__ xlb, unsigned short* __restrict__ xrb,
                        int M) {
    __shared__ short As[64 * 128];
    int row0 = blockIdx.x * 64;
    int sel = blockIdx.y;
    const unsigned short* BT = sel ? WrT : WlT;
    unsigned short* Cb = sel ? xrb : xlb;
    int t = threadIdx.x;
    {
        int row = t >> 2, c0 = (t & 3) * 32;
        int gr = row0 + row;
        int sw = (row & 7) << 4;
        const float* src = A + (size_t)gr * 128 + c0;
        #pragma unroll
        for (int i = 0; i < 4; ++i) {
            bf16x8 v;
            if (gr < M) {
                const float4* p = (const float4*)(src + i * 8);
                float4 f0 = p[0], f1 = p[1];
                v[0] = f2bf(f0.x); v[1] = f2bf(f0.y); v[2] = f2bf(f0.z); v[3] = f2bf(f0.w);
                v[4] = f2bf(f1.x); v[5] = f2bf(f1.y); v[6] = f2bf(f1.z); v[7] = f2bf(f1.w);
            } else {
                #pragma unroll
                for (int j = 0; j < 8; ++j) v[j] = 0;
            }
            int off = row * 256 + (((c0 + i * 8) * 2) ^ sw);
            *(bf16x8*)((char*)As + off) = v;
        }
    }
    __syncthreads();

    int w = t >> 6, l = t & 63;
    int lr = l & 15, lk = l >> 4;

    #pragma unroll
    for (int ch = 0; ch < 2; ++ch) {
        int col0 = ch * 256 + w * 64;
        f32x4 acc[4][4];
        #pragma unroll
        for (int mi = 0; mi < 4; ++mi)
            #pragma unroll
            for (int fj = 0; fj < 4; ++fj)
                #pragma unroll
                for (int q = 0; q < 4; ++q) acc[mi][fj][q] = 0.f;

        #pragma unroll
        for (int k0 = 0; k0 < 4; ++k0) {
            bf16x8 a4[4];
            #pragma unroll
            for (int mi = 0; mi < 4; ++mi) {
                int row = mi * 16 + lr;
                int off = row * 256 + ((k0 * 64 + lk * 16) ^ ((row & 7) << 4));
                a4[mi] = *(const bf16x8*)((const char*)As + off);
            }
            #pragma unroll
            for (int fj = 0; fj < 4; ++fj) {
                bf16x8 b = *(const bf16x8*)(BT + (size_t)(col0 + fj * 16 + lr) * 128 + k0 * 32 + lk * 8);
                #pragma unroll
                for (int mi = 0; mi < 4; ++mi)
                    acc[mi][fj] = __builtin_amdgcn_mfma_f32_16x16x32_bf16(a4[mi], b, acc[mi][fj], 0, 0, 0);
            }
        }
        #pragma unroll
        for (int mi = 0; mi < 4; ++mi) {
            #pragma unroll
            for (int reg = 0; reg < 4; ++reg) {
                int r = row0 + mi * 16 + lk * 4 + reg;
                if (r < M) {
                    unsigned short* cp = Cb + (size_t)r * 512 + col0 + lr;
                    #pragma unroll
                    for (int fj = 0; fj < 4; ++fj) cp[fj * 16] = f2bf(acc[mi][fj][reg]);
                }
            }
        }
    }
}

// ---------------- fused: edge GEMM + scoring + interior softmax/aggregation ----------------
#define PREF(R, CB, SLOT) { \
    int s_ = s_src[R], d_ = s_dst[R]; \
    const bf16x8* xp_ = (const bf16x8*)(xlb + (size_t)s_ * 512 + (CB) + q * 16); \
    pa0[SLOT] = xp_[0]; pa1[SLOT] = xp_[1]; \
    const bf16x8* rp_ = (const bf16x8*)(xrb + (size_t)d_ * 512 + (CB) + q * 16); \
    pb0[SLOT] = rp_[0]; pb1[SLOT] = rp_[1]; }

__global__ void k_fused(const int* __restrict__ src_s, const int* __restrict__ dst_s,
                        const int* __restrict__ rowptr,
                        const unsigned short* __restrict__ eab,
                        const unsigned short* __restrict__ WeT,
                        const unsigned short* __restrict__ xlb,
                        const unsigned short* __restrict__ xrb,
                        const float* __restrict__ att, const float* __restrict__ bias,
                        float* __restrict__ logits, float* __restrict__ out) {
    __shared__ short As[64 * 128];
    __shared__ unsigned short xeT[4][16][72];   // bf16, 144B row stride (16B aligned)
    __shared__ float att_s[512];
    __shared__ float lg[64][8];
    __shared__ int s_src[64], s_dst[64];
    __shared__ int own_node[64], own_beg[64], own_len[64];
    __shared__ int n_own;
    int row0 = blockIdx.x * 64;
    int t = threadIdx.x;

    if (t == 0) n_own = 0;
    __syncthreads();

    // async staged A-tile: contiguous bf16 rows of eab, inverse-swizzled source
    {
        int l = t & 63;
        int c_base = (t >> 6) * 4;
        #pragma unroll
        for (int i = 0; i < 4; ++i) {
            int c = c_base + i;
            int row_local = c * 4 + (l >> 4);
            int grow = row0 + row_local;
            if (grow > M_TOT - 1) grow = M_TOT - 1;
            int chunk = (l & 15) ^ (row_local & 7);
            const char* src = (const char*)eab + (size_t)grow * 256 + chunk * 16;
            char* dst = (char*)As + c * 1024;
            GLOAD_LDS16(src, dst);
        }
    }

    if (t < 64) {
        int p = row0 + t;
        int s = 0, d = 0;
        if (p < M_TOT) {
            s = src_s[p]; d = dst_s[p];
            int pb = rowptr[d], pe = rowptr[d + 1];
            if (pb == p && pe <= row0 + 64) {          // interior segment, first row
                int idx = atomicAdd(&n_own, 1);
                own_node[idx] = d; own_beg[idx] = t; own_len[idx] = pe - pb;
            }
        }
        s_src[t] = s; s_dst[t] = d;
    }
    att_s[t] = att[t];
    att_s[t + 256] = att[t + 256];

    asm volatile("s_waitcnt vmcnt(0)");
    __syncthreads();

    int w = t >> 6, l = t & 63;
    int lr = l & 15, lk = l >> 4;
    int eloc = l >> 2, q = l & 3;   // epilogue: 4 lanes per edge
    int cb0 = w * 128;              // head pair base channel

    bf16x8 pa0[2], pa1[2], pb0[2], pb1[2];
    f32x4 acc[4][4];

    PREF(eloc, cb0, 0);

    #pragma unroll
    for (int hh = 0; hh < 2; ++hh) {
        int cb = cb0 + hh * 64;
        int h = w * 2 + hh;

        #pragma unroll
        for (int mi = 0; mi < 4; ++mi)
            #pragma unroll
            for (int fj = 0; fj < 4; ++fj)
                #pragma unroll
                for (int qq = 0; qq < 4; ++qq) acc[mi][fj][qq] = 0.f;

        #pragma unroll
        for (int k0 = 0; k0 < 4; ++k0) {
            bf16x8 a4[4];
            #pragma unroll
            for (int mi = 0; mi < 4; ++mi) {
                int row = mi * 16 + lr;
                int off = row * 256 + ((k0 * 64 + lk * 16) ^ ((row & 7) << 4));
                a4[mi] = *(const bf16x8*)((const char*)As + off);
            }
            #pragma unroll
            for (int fj = 0; fj < 4; ++fj) {
                bf16x8 b = *(const bf16x8*)(WeT + (size_t)(cb + fj * 16 + lr) * 128 + k0 * 32 + lk * 8);
                #pragma unroll
                for (int mi = 0; mi < 4; ++mi)
                    acc[mi][fj] = __builtin_amdgcn_mfma_f32_16x16x32_bf16(a4[mi], b, acc[mi][fj], 0, 0, 0);
            }
        }

        #pragma unroll
        for (int mi = 0; mi < 4; ++mi) {
            if (mi < 3) { PREF(mi * 16 + 16 + eloc, cb, (mi + 1) & 1); }
            else if (hh == 0) { PREF(eloc, cb + 64, 0); }

            #pragma unroll
            for (int fj = 0; fj < 4; ++fj)
                #pragma unroll
                for (int reg = 0; reg < 4; ++reg)
                    xeT[w][lk * 4 + reg][fj * 16 + lr] = f2bf_trunc(acc[mi][fj][reg]);

            const bf16x8 ca0 = pa0[mi & 1], ca1 = pa1[mi & 1];
            const bf16x8 cb0v = pb0[mi & 1], cb1v = pb1[mi & 1];

            bf16x8 x0 = *(const bf16x8*)&xeT[w][eloc][q * 16];
            bf16x8 x1 = *(const bf16x8*)&xeT[w][eloc][q * 16 + 8];

            float sum = 0.f;
            #pragma unroll
            for (int sg = 0; sg < 4; ++sg) {
                float4 av = *(const float4*)&att_s[cb + q * 16 + sg * 4];
                float v0 = bfx(x0, x1, sg * 4 + 0) + bfx(ca0, ca1, sg * 4 + 0) + bfx(cb0v, cb1v, sg * 4 + 0);
                float v1 = bfx(x0, x1, sg * 4 + 1) + bfx(ca0, ca1, sg * 4 + 1) + bfx(cb0v, cb1v, sg * 4 + 1);
                float v2 = bfx(x0, x1, sg * 4 + 2) + bfx(ca0, ca1, sg * 4 + 2) + bfx(cb0v, cb1v, sg * 4 + 2);
                float v3 = bfx(x0, x1, sg * 4 + 3) + bfx(ca0, ca1, sg * 4 + 3) + bfx(cb0v, cb1v, sg * 4 + 3);
                v0 = (v0 > 0.f) ? v0 : v0 * NEG_SLOPE;
                v1 = (v1 > 0.f) ? v1 : v1 * NEG_SLOPE;
                v2 = (v2 > 0.f) ? v2 : v2 * NEG_SLOPE;
                v3 = (v3 > 0.f) ? v3 : v3 * NEG_SLOPE;
                sum = fmaf(av.x, v0, sum);
                sum = fmaf(av.y, v1, sum);
                sum = fmaf(av.z, v2, sum);
                sum = fmaf(av.w, v3, sum);
            }
            sum += __shfl_xor(sum, 1, 64);
            sum += __shfl_xor(sum, 2, 64);
            if (q == 0) {
                int rloc = mi * 16 + eloc;
                lg[rloc][h] = sum;
                int p = row0 + rloc;
                if (p < M_TOT) logits[(size_t)p * 8 + h] = sum;
            }
        }
    }
    __syncthreads();

    // interior softmax + aggregation (owned segments, logits in LDS, xl hot in cache)
    {
        int lane = t & 63;
        int h = lane >> 3;
        for (int o = w; o < n_own; o += 4) {
            int d = own_node[o], rb = own_beg[o], len = own_len[o];
            float m = -3.4e38f;
            for (int j = 0; j < len; ++j) m = fmaxf(m, lg[rb + j][h]);
            float den = 0.f;
            for (int j = 0; j < len; ++j) den += __expf(lg[rb + j][h] - m);
            float rden = 1.f / den;
            float ac[8] = {};
            bf16x8 v_nxt = *(const bf16x8*)(xlb + (size_t)s_src[rb] * 512 + lane * 8);
            for (int j = 0; j < len; ++j) {
                bf16x8 v = v_nxt;
                if (j + 1 < len)
                    v_nxt = *(const bf16x8*)(xlb + (size_t)s_src[rb + j + 1] * 512 + lane * 8);
                float alpha = __expf(lg[rb + j][h] - m) * rden;
                #pragma unroll
                for (int jj = 0; jj < 8; ++jj) ac[jj] = fmaf(alpha, bf2f((unsigned short)v[jj]), ac[jj]);
            }
            float4* op = (float4*)(out + (size_t)d * 512 + lane * 8);
            const float4* bp = (const float4*)(bias + lane * 8);
            float4 bv0 = bp[0], bv1 = bp[1];
            float4 r0 = { ac[0] + bv0.x, ac[1] + bv0.y, ac[2] + bv0.z, ac[3] + bv0.w };
            float4 r1 = { ac[4] + bv1.x, ac[5] + bv1.y, ac[6] + bv1.z, ac[7] + bv1.w };
            op[0] = r0; op[1] = r1;
        }
    }
}

// ---------------- cleanup: boundary segments only ----------------
__global__ void k_cleanup(const int* __restrict__ rowptr, const int* __restrict__ src_s,
                          const float* __restrict__ logits,
                          const unsigned short* __restrict__ xlb, const float* __restrict__ bias,
                          float* __restrict__ out) {
    int node = (blockIdx.x * blockDim.x + threadIdx.x) >> 6;
    int lane = threadIdx.x & 63;
    if (node >= N_NODES) return;
    int beg = rowptr[node], end = rowptr[node + 1];
    if ((beg >> 6) == ((end - 1) >> 6)) return;   // interior: handled in k_fused
    int h = lane >> 3;

    float m = -3.4e38f;
    for (int p = beg; p < end; ++p) m = fmaxf(m, logits[(size_t)p * 8 + h]);
    float den = 0.f;
    for (int p = beg; p < end; ++p) den += __expf(logits[(size_t)p * 8 + h] - m);
    float rden = 1.f / den;

    float acc[8] = {};
    bf16x8 v_nxt = *(const bf16x8*)(xlb + (size_t)src_s[beg] * 512 + lane * 8);
    for (int p = beg; p < end; ++p) {
        bf16x8 v = v_nxt;
        float lgv = logits[(size_t)p * 8 + h];
        if (p + 1 < end)
            v_nxt = *(const bf16x8*)(xlb + (size_t)src_s[p + 1] * 512 + lane * 8);
        float alpha = __expf(lgv - m) * rden;
        #pragma unroll
        for (int j = 0; j < 8; ++j) acc[j] = fmaf(alpha, bf2f((unsigned short)v[j]), acc[j]);
    }
    float4* op = (float4*)(out + (size_t)node * 512 + lane * 8);
    const float4* bp = (const float4*)(bias + lane * 8);
    float4 bv0 = bp[0], bv1 = bp[1];
    float4 r0 = { acc[0] + bv0.x, acc[1] + bv0.y, acc[2] + bv0.z, acc[3] + bv0.w };
    float4 r1 = { acc[4] + bv1.x, acc[5] + bv1.y, acc[6] + bv1.z, acc[7] + bv1.w };
    op[0] = r0; op[1] = r1;
}

extern "C" void kernel_launch(void* const* d_in, const int* in_sizes, int n_in,
                              void* d_out, int out_size, void* d_ws, size_t ws_size,
                              hipStream_t stream) {
    const float* x    = (const float*)d_in[0];
    const int*   ei   = (const int*)d_in[1];
    const float* ea   = (const float*)d_in[2];
    const float* Wl   = (const float*)d_in[3];
    const float* Wr   = (const float*)d_in[4];
    const float* We   = (const float*)d_in[5];
    const float* att  = (const float*)d_in[6];
    const float* bias = (const float*)d_in[7];
    float* out = (float*)d_out;

    unsigned short* xlb = (unsigned short*)d_ws;             // N*512 bf16
    unsigned short* xrb = xlb + (size_t)N_NODES * HC;        // N*512 bf16
    unsigned short* WlT = xrb + (size_t)N_NODES * HC;        // 512*128 bf16
    unsigned short* WrT = WlT + HC * IN_CH;
    unsigned short* WeT = WrT + HC * IN_CH;
    unsigned short* eab = WeT + HC * IN_CH;                  // M_TOT*128 bf16
    float* logits    = (float*)(eab + (size_t)M_TOT * IN_CH); // M_TOT*8 f32
    int* deg         = (int*)(logits + (size_t)M_TOT * 8);
    int* rowptr      = deg + N_NODES;
    int* cursor      = rowptr + N_NODES + 1;
    int* eidx        = cursor + N_NODES;
    int* src_s       = eidx + M_TOT;
    int* dst_s       = src_s + M_TOT;
    int* bsum        = dst_s + M_TOT;
    int* boff        = bsum + NCHUNK;

    const int B = 256;
    hipMemsetAsync(deg, 0, N_NODES * sizeof(int), stream);
    k_deg<<<(E_EDGES + B - 1) / B, B, 0, stream>>>(ei, deg);
    k_scan1<<<NCHUNK, B, 0, stream>>>(deg, bsum);
    k_scan2<<<1, 64, 0, stream>>>(bsum, boff);
    k_scan3<<<NCHUNK, B, 0, stream>>>(deg, boff, rowptr, cursor, eidx, src_s, dst_s);
    k_fill<<<(E_EDGES + B - 1) / B, B, 0, stream>>>(ei, cursor, eidx, src_s, dst_s);
    k_prep<<<((size_t)N_NODES * 128 + B - 1) / B, B, 0, stream>>>(rowptr, eidx, ea, eab);
    k_trans3<<<dim3((HC * IN_CH + B - 1) / B, 3), B, 0, stream>>>(Wl, Wr, We, WlT, WrT, WeT);
    k_gemm2<<<dim3((N_NODES + 63) / 64, 2), B, 0, stream>>>(x, WlT, WrT, xlb, xrb, N_NODES);
    k_fused<<<(M_TOT + 63) / 64, B, 0, stream>>>(src_s, dst_s, rowptr, eab, WeT,
                                                 xlb, xrb, att, bias, logits, out);
    k_cleanup<<<((size_t)N_NODES * 64 + B - 1) / B, B, 0, stream>>>(rowptr, src_s, logits,
                                                                    xlb, bias, out);
}

// Round 9
// 258.662 us; speedup vs baseline: 1.1190x; 1.1190x over previous
//
#include <hip/hip_runtime.h>

#define N_NODES 20000
#define E_EDGES 160000
#define IN_CH 128
#define H_HEADS 8
#define C_CH 64
#define HC 512
#define M_TOT (E_EDGES + N_NODES)
#define NEG_SLOPE 0.2f
#define NCHUNK ((N_NODES + 255) / 256)

typedef __attribute__((ext_vector_type(8))) short bf16x8;
typedef __attribute__((ext_vector_type(4))) float f32x4;

__device__ __forceinline__ unsigned short f2bf(float f) {
    unsigned u = __float_as_uint(f);
    unsigned r = (u + 0x7FFFu + ((u >> 16) & 1u)) >> 16;   // RNE
    return (unsigned short)r;
}
__device__ __forceinline__ unsigned short f2bf_trunc(float f) {
    return (unsigned short)(__float_as_uint(f) >> 16);     // 1-inst truncate (xeT only)
}
__device__ __forceinline__ float bf2f(unsigned short s) {
    return __uint_as_float((unsigned)s << 16);
}
__device__ __forceinline__ float bfx(const bf16x8& v0, const bf16x8& v1, int idx) {
    return bf2f((unsigned short)((idx < 8) ? v0[idx] : v1[idx - 8]));
}

#define GLOAD_LDS16(gsrc, ldst) \
    __builtin_amdgcn_global_load_lds((const __attribute__((address_space(1))) void*)(gsrc), \
                                     (__attribute__((address_space(3))) void*)(ldst), 16, 0, 0)

// ---------------- CSR build ----------------
__global__ void k_deg(const int* __restrict__ ei, int* __restrict__ deg) {
    int e = blockIdx.x * blockDim.x + threadIdx.x;
    if (e >= E_EDGES) return;
    atomicAdd(&deg[ei[E_EDGES + e]], 1);
}

__global__ void k_scan1(const int* __restrict__ deg, int* __restrict__ bsum) {
    __shared__ int red[256];
    int tid = threadIdx.x;
    int i = blockIdx.x * 256 + tid;
    red[tid] = (i < N_NODES) ? deg[i] + 1 : 0;
    __syncthreads();
    for (int off = 128; off > 0; off >>= 1) {
        if (tid < off) red[tid] += red[tid + off];
        __syncthreads();
    }
    if (tid == 0) bsum[blockIdx.x] = red[0];
}

__global__ void k_scan2(const int* __restrict__ bsum, int* __restrict__ boff) {
    if (threadIdx.x == 0) {
        int run = 0;
        for (int b = 0; b < NCHUNK; ++b) { boff[b] = run; run += bsum[b]; }
    }
}

__global__ void k_scan3(const int* __restrict__ deg, const int* __restrict__ boff,
                        int* __restrict__ rowptr, int* __restrict__ cursor,
                        int* __restrict__ eidx, int* __restrict__ src_s,
                        int* __restrict__ dst_s) {
    __shared__ int buf[256];
    int tid = threadIdx.x;
    int i = blockIdx.x * 256 + tid;
    int v = (i < N_NODES) ? deg[i] + 1 : 0;
    buf[tid] = v;
    __syncthreads();
    for (int off = 1; off < 256; off <<= 1) {
        int tv = (tid >= off) ? buf[tid - off] : 0;
        __syncthreads();
        buf[tid] += tv;
        __syncthreads();
    }
    if (i < N_NODES) {
        int excl = boff[blockIdx.x] + buf[tid] - v;
        rowptr[i] = excl;
        eidx[excl] = E_EDGES + i;   // self-loop edge in slot 0
        src_s[excl] = i;
        dst_s[excl] = i;
        cursor[i] = excl + 1;
        if (i == N_NODES - 1) rowptr[N_NODES] = excl + v;   // == M_TOT
    }
}

__global__ void k_fill(const int* __restrict__ ei, int* __restrict__ cursor,
                       int* __restrict__ eidx, int* __restrict__ src_s,
                       int* __restrict__ dst_s) {
    int e = blockIdx.x * blockDim.x + threadIdx.x;
    if (e >= E_EDGES) return;
    int d = ei[E_EDGES + e];
    int slot = atomicAdd(&cursor[d], 1);
    eidx[slot] = e;
    src_s[slot] = ei[e];
    dst_s[slot] = d;
}

// ---------------- k_prep: eab[p][128] bf16 in CSR order + self-loop mean (R6 form) ----------------
__global__ void k_prep(const int* __restrict__ rowptr, const int* __restrict__ eidx,
                       const float* __restrict__ ea, unsigned short* __restrict__ eab) {
    int node = (blockIdx.x * blockDim.x + threadIdx.x) >> 6;
    int lane = threadIdx.x & 63;
    if (node >= N_NODES) return;
    int beg = rowptr[node], end = rowptr[node + 1];
    int cnt = end - beg - 1;
    float s0 = 0.f, s1 = 0.f;
    if (beg + 1 < end) {
        const float* p_nxt = ea + (size_t)eidx[beg + 1] * 128 + lane;
        for (int p = beg + 1; p < end; ++p) {
            const float* cur = p_nxt;
            if (p + 1 < end) p_nxt = ea + (size_t)eidx[p + 1] * 128 + lane;
            float v0 = cur[0], v1 = cur[64];
            s0 += v0; s1 += v1;
            eab[(size_t)p * 128 + lane] = f2bf(v0);
            eab[(size_t)p * 128 + 64 + lane] = f2bf(v1);
        }
    }
    float inv = 1.f / fmaxf((float)cnt, 1.f);
    eab[(size_t)beg * 128 + lane] = f2bf(s0 * inv);
    eab[(size_t)beg * 128 + 64 + lane] = f2bf(s1 * inv);
}

// ---------------- weight transpose + bf16 (all three) ----------------
__global__ void k_trans3(const float* __restrict__ Wl, const float* __restrict__ Wr,
                         const float* __restrict__ We,
                         unsigned short* __restrict__ WlT, unsigned short* __restrict__ WrT,
                         unsigned short* __restrict__ WeT) {
    int idx = blockIdx.x * blockDim.x + threadIdx.x;
    if (idx >= HC * IN_CH) return;
    int m = blockIdx.y;
    const float* W = (m == 0) ? Wl : (m == 1) ? Wr : We;
    unsigned short* WT = (m == 0) ? WlT : (m == 1) ? WrT : WeT;
    int n = idx >> 7, k = idx & 127;
    WT[idx] = f2bf(W[(size_t)k * HC + n]);
}

// ---------------- merged dual MFMA GEMM (R6 form: grid.y=4) ----------------
__global__ void k_gemm2(const float* __restrict__ A,
                        const unsigned short* __restrict__ WlT,
                        const unsigned short* __restrict__ WrT,
                        unsigned short* __restrict__ xlb, unsigned short* __restrict__ xrb,
                        int M) {
    __shared__ short As[64 * 128];
    int row0 = blockIdx.x * 64;
    int sel = blockIdx.y >> 1;
    const unsigned short* BT = sel ? WrT : WlT;
    unsigned short* Cb = sel ? xrb : xlb;
    int t = threadIdx.x;
    {
        int row = t >> 2, c0 = (t & 3) * 32;
        int gr = row0 + row;
        int sw = (row & 7) << 4;
        const float* src = A + (size_t)gr * 128 + c0;
        #pragma unroll
        for (int i = 0; i < 4; ++i) {
            bf16x8 v;
            if (gr < M) {
                const float4* p = (const float4*)(src + i * 8);
                float4 f0 = p[0], f1 = p[1];
                v[0] = f2bf(f0.x); v[1] = f2bf(f0.y); v[2] = f2bf(f0.z); v[3] = f2bf(f0.w);
                v[4] = f2bf(f1.x); v[5] = f2bf(f1.y); v[6] = f2bf(f1.z); v[7] = f2bf(f1.w);
            } else {
                #pragma unroll
                for (int j = 0; j < 8; ++j) v[j] = 0;
            }
            int off = row * 256 + (((c0 + i * 8) * 2) ^ sw);
            *(bf16x8*)((char*)As + off) = v;
        }
    }
    __syncthreads();

    int w = t >> 6, l = t & 63;
    int lr = l & 15, lk = l >> 4;
    int col0 = (blockIdx.y & 1) * 256 + w * 64;

    f32x4 acc[4][4];
    #pragma unroll
    for (int mi = 0; mi < 4; ++mi)
        #pragma unroll
        for (int fj = 0; fj < 4; ++fj)
            #pragma unroll
            for (int q = 0; q < 4; ++q) acc[mi][fj][q] = 0.f;

    #pragma unroll
    for (int k0 = 0; k0 < 4; ++k0) {
        bf16x8 a4[4];
        #pragma unroll
        for (int mi = 0; mi < 4; ++mi) {
            int row = mi * 16 + lr;
            int off = row * 256 + ((k0 * 64 + lk * 16) ^ ((row & 7) << 4));
            a4[mi] = *(const bf16x8*)((const char*)As + off);
        }
        #pragma unroll
        for (int fj = 0; fj < 4; ++fj) {
            bf16x8 b = *(const bf16x8*)(BT + (size_t)(col0 + fj * 16 + lr) * 128 + k0 * 32 + lk * 8);
            #pragma unroll
            for (int mi = 0; mi < 4; ++mi)
                acc[mi][fj] = __builtin_amdgcn_mfma_f32_16x16x32_bf16(a4[mi], b, acc[mi][fj], 0, 0, 0);
        }
    }
    #pragma unroll
    for (int mi = 0; mi < 4; ++mi) {
        #pragma unroll
        for (int reg = 0; reg < 4; ++reg) {
            int r = row0 + mi * 16 + lk * 4 + reg;
            if (r < M) {
                unsigned short* cp = Cb + (size_t)r * 512 + col0 + lr;
                #pragma unroll
                for (int fj = 0; fj < 4; ++fj) cp[fj * 16] = f2bf(acc[mi][fj][reg]);
            }
        }
    }
}

// ---------------- fused: edge GEMM + scoring + interior softmax/aggregation ----------------
// mi-split accumulator (acc[2][4] = 32 AGPR) for occupancy; coalesced logits write.
#define PREF(R, CB, SLOT) { \
    int s_ = s_src[R], d_ = s_dst[R]; \
    const bf16x8* xp_ = (const bf16x8*)(xlb + (size_t)s_ * 512 + (CB) + q * 16); \
    pa0[SLOT] = xp_[0]; pa1[SLOT] = xp_[1]; \
    const bf16x8* rp_ = (const bf16x8*)(xrb + (size_t)d_ * 512 + (CB) + q * 16); \
    pb0[SLOT] = rp_[0]; pb1[SLOT] = rp_[1]; }

__global__ void k_fused(const int* __restrict__ src_s, const int* __restrict__ dst_s,
                        const int* __restrict__ rowptr,
                        const unsigned short* __restrict__ eab,
                        const unsigned short* __restrict__ WeT,
                        const unsigned short* __restrict__ xlb,
                        const unsigned short* __restrict__ xrb,
                        const float* __restrict__ att, const float* __restrict__ bias,
                        float* __restrict__ logits, float* __restrict__ out) {
    __shared__ short As[64 * 128];
    __shared__ unsigned short xeT[4][16][72];   // bf16, 144B row stride
    __shared__ float att_s[512];
    __shared__ float lg[64][8];
    __shared__ int s_src[64], s_dst[64];
    __shared__ int own_node[64], own_beg[64], own_len[64];
    __shared__ int n_own;
    int row0 = blockIdx.x * 64;
    int t = threadIdx.x;

    if (t == 0) n_own = 0;
    __syncthreads();

    // async staged A-tile: contiguous bf16 rows of eab, inverse-swizzled source
    {
        int l = t & 63;
        int c_base = (t >> 6) * 4;
        #pragma unroll
        for (int i = 0; i < 4; ++i) {
            int c = c_base + i;
            int row_local = c * 4 + (l >> 4);
            int grow = row0 + row_local;
            if (grow > M_TOT - 1) grow = M_TOT - 1;
            int chunk = (l & 15) ^ (row_local & 7);
            const char* src = (const char*)eab + (size_t)grow * 256 + chunk * 16;
            char* dst = (char*)As + c * 1024;
            GLOAD_LDS16(src, dst);
        }
    }

    if (t < 64) {
        int p = row0 + t;
        int s = 0, d = 0;
        if (p < M_TOT) {
            s = src_s[p]; d = dst_s[p];
            int pb = rowptr[d], pe = rowptr[d + 1];
            if (pb == p && pe <= row0 + 64) {          // interior segment, first row
                int idx = atomicAdd(&n_own, 1);
                own_node[idx] = d; own_beg[idx] = t; own_len[idx] = pe - pb;
            }
        }
        s_src[t] = s; s_dst[t] = d;
    }
    att_s[t] = att[t];
    att_s[t + 256] = att[t + 256];

    asm volatile("s_waitcnt vmcnt(0)");
    __syncthreads();

    int w = t >> 6, l = t & 63;
    int lr = l & 15, lk = l >> 4;
    int eloc = l >> 2, q = l & 3;   // epilogue: 4 lanes per edge
    int cb0 = w * 128;              // head pair base channel

    bf16x8 pa0[2], pa1[2], pb0[2], pb1[2];

    PREF(eloc, cb0, 0);

    #pragma unroll
    for (int hh = 0; hh < 2; ++hh) {
        int cb = cb0 + hh * 64;
        int h = w * 2 + hh;

        #pragma unroll
        for (int mih = 0; mih < 2; ++mih) {
            f32x4 acc[2][4];
            #pragma unroll
            for (int mi2 = 0; mi2 < 2; ++mi2)
                #pragma unroll
                for (int fj = 0; fj < 4; ++fj)
                    #pragma unroll
                    for (int qq = 0; qq < 4; ++qq) acc[mi2][fj][qq] = 0.f;

            #pragma unroll
            for (int k0 = 0; k0 < 4; ++k0) {
                bf16x8 a4[2];
                #pragma unroll
                for (int mi2 = 0; mi2 < 2; ++mi2) {
                    int row = (mih * 2 + mi2) * 16 + lr;
                    int off = row * 256 + ((k0 * 64 + lk * 16) ^ ((row & 7) << 4));
                    a4[mi2] = *(const bf16x8*)((const char*)As + off);
                }
                #pragma unroll
                for (int fj = 0; fj < 4; ++fj) {
                    bf16x8 b = *(const bf16x8*)(WeT + (size_t)(cb + fj * 16 + lr) * 128 + k0 * 32 + lk * 8);
                    #pragma unroll
                    for (int mi2 = 0; mi2 < 2; ++mi2)
                        acc[mi2][fj] = __builtin_amdgcn_mfma_f32_16x16x32_bf16(a4[mi2], b, acc[mi2][fj], 0, 0, 0);
                }
            }

            #pragma unroll
            for (int mi2 = 0; mi2 < 2; ++mi2) {
                int mi = mih * 2 + mi2;
                // prefetch next round (double-buffered; static indices under unroll)
                if (mi < 3) { PREF(mi * 16 + 16 + eloc, cb, (mi + 1) & 1); }
                else if (hh == 0) { PREF(eloc, cb + 64, 0); }

                #pragma unroll
                for (int fj = 0; fj < 4; ++fj)
                    #pragma unroll
                    for (int reg = 0; reg < 4; ++reg)
                        xeT[w][lk * 4 + reg][fj * 16 + lr] = f2bf_trunc(acc[mi2][fj][reg]);

                const bf16x8 ca0 = pa0[mi & 1], ca1 = pa1[mi & 1];
                const bf16x8 cb0v = pb0[mi & 1], cb1v = pb1[mi & 1];

                bf16x8 x0 = *(const bf16x8*)&xeT[w][eloc][q * 16];
                bf16x8 x1 = *(const bf16x8*)&xeT[w][eloc][q * 16 + 8];

                float sum = 0.f;
                #pragma unroll
                for (int sg = 0; sg < 4; ++sg) {
                    float4 av = *(const float4*)&att_s[cb + q * 16 + sg * 4];
                    float v0 = bfx(x0, x1, sg * 4 + 0) + bfx(ca0, ca1, sg * 4 + 0) + bfx(cb0v, cb1v, sg * 4 + 0);
                    float v1 = bfx(x0, x1, sg * 4 + 1) + bfx(ca0, ca1, sg * 4 + 1) + bfx(cb0v, cb1v, sg * 4 + 1);
                    float v2 = bfx(x0, x1, sg * 4 + 2) + bfx(ca0, ca1, sg * 4 + 2) + bfx(cb0v, cb1v, sg * 4 + 2);
                    float v3 = bfx(x0, x1, sg * 4 + 3) + bfx(ca0, ca1, sg * 4 + 3) + bfx(cb0v, cb1v, sg * 4 + 3);
                    v0 = (v0 > 0.f) ? v0 : v0 * NEG_SLOPE;
                    v1 = (v1 > 0.f) ? v1 : v1 * NEG_SLOPE;
                    v2 = (v2 > 0.f) ? v2 : v2 * NEG_SLOPE;
                    v3 = (v3 > 0.f) ? v3 : v3 * NEG_SLOPE;
                    sum = fmaf(av.x, v0, sum);
                    sum = fmaf(av.y, v1, sum);
                    sum = fmaf(av.z, v2, sum);
                    sum = fmaf(av.w, v3, sum);
                }
                sum += __shfl_xor(sum, 1, 64);
                sum += __shfl_xor(sum, 2, 64);
                if (q == 0) lg[mi * 16 + eloc][h] = sum;
            }
        }
    }
    __syncthreads();

    // coalesced logits write: 64 rows x 8 heads = 512 floats contiguous
    {
        int nval = (M_TOT - row0 < 64 ? M_TOT - row0 : 64) * 8;
        if (t * 2 < nval) {
            const float* lf = (const float*)lg;
            float2 v = { lf[t * 2], lf[t * 2 + 1] };
            *(float2*)(logits + (size_t)row0 * 8 + t * 2) = v;
        }
    }

    // interior softmax + aggregation (owned segments, logits in LDS, xl hot in cache)
    {
        int lane = t & 63;
        int h = lane >> 3;
        for (int o = w; o < n_own; o += 4) {
            int d = own_node[o], rb = own_beg[o], len = own_len[o];
            float m = -3.4e38f;
            for (int j = 0; j < len; ++j) m = fmaxf(m, lg[rb + j][h]);
            float den = 0.f;
            for (int j = 0; j < len; ++j) den += __expf(lg[rb + j][h] - m);
            float rden = 1.f / den;
            float ac[8] = {};
            bf16x8 v_nxt = *(const bf16x8*)(xlb + (size_t)s_src[rb] * 512 + lane * 8);
            for (int j = 0; j < len; ++j) {
                bf16x8 v = v_nxt;
                if (j + 1 < len)
                    v_nxt = *(const bf16x8*)(xlb + (size_t)s_src[rb + j + 1] * 512 + lane * 8);
                float alpha = __expf(lg[rb + j][h] - m) * rden;
                #pragma unroll
                for (int jj = 0; jj < 8; ++jj) ac[jj] = fmaf(alpha, bf2f((unsigned short)v[jj]), ac[jj]);
            }
            float4* op = (float4*)(out + (size_t)d * 512 + lane * 8);
            const float4* bp = (const float4*)(bias + lane * 8);
            float4 bv0 = bp[0], bv1 = bp[1];
            float4 r0 = { ac[0] + bv0.x, ac[1] + bv0.y, ac[2] + bv0.z, ac[3] + bv0.w };
            float4 r1 = { ac[4] + bv1.x, ac[5] + bv1.y, ac[6] + bv1.z, ac[7] + bv1.w };
            op[0] = r0; op[1] = r1;
        }
    }
}

// ---------------- cleanup: boundary segments only ----------------
__global__ void k_cleanup(const int* __restrict__ rowptr, const int* __restrict__ src_s,
                          const float* __restrict__ logits,
                          const unsigned short* __restrict__ xlb, const float* __restrict__ bias,
                          float* __restrict__ out) {
    int node = (blockIdx.x * blockDim.x + threadIdx.x) >> 6;
    int lane = threadIdx.x & 63;
    if (node >= N_NODES) return;
    int beg = rowptr[node], end = rowptr[node + 1];
    if ((beg >> 6) == ((end - 1) >> 6)) return;   // interior: handled in k_fused
    int h = lane >> 3;

    float m = -3.4e38f;
    for (int p = beg; p < end; ++p) m = fmaxf(m, logits[(size_t)p * 8 + h]);
    float den = 0.f;
    for (int p = beg; p < end; ++p) den += __expf(logits[(size_t)p * 8 + h] - m);
    float rden = 1.f / den;

    float acc[8] = {};
    bf16x8 v_nxt = *(const bf16x8*)(xlb + (size_t)src_s[beg] * 512 + lane * 8);
    for (int p = beg; p < end; ++p) {
        bf16x8 v = v_nxt;
        float lgv = logits[(size_t)p * 8 + h];
        if (p + 1 < end)
            v_nxt = *(const bf16x8*)(xlb + (size_t)src_s[p + 1] * 512 + lane * 8);
        float alpha = __expf(lgv - m) * rden;
        #pragma unroll
        for (int j = 0; j < 8; ++j) acc[j] = fmaf(alpha, bf2f((unsigned short)v[j]), acc[j]);
    }
    float4* op = (float4*)(out + (size_t)node * 512 + lane * 8);
    const float4* bp = (const float4*)(bias + lane * 8);
    float4 bv0 = bp[0], bv1 = bp[1];
    float4 r0 = { acc[0] + bv0.x, acc[1] + bv0.y, acc[2] + bv0.z, acc[3] + bv0.w };
    float4 r1 = { acc[4] + bv1.x, acc[5] + bv1.y, acc[6] + bv1.z, acc[7] + bv1.w };
    op[0] = r0; op[1] = r1;
}

extern "C" void kernel_launch(void* const* d_in, const int* in_sizes, int n_in,
                              void* d_out, int out_size, void* d_ws, size_t ws_size,
                              hipStream_t stream) {
    const float* x    = (const float*)d_in[0];
    const int*   ei   = (const int*)d_in[1];
    const float* ea   = (const float*)d_in[2];
    const float* Wl   = (const float*)d_in[3];
    const float* Wr   = (const float*)d_in[4];
    const float* We   = (const float*)d_in[5];
    const float* att  = (const float*)d_in[6];
    const float* bias = (const float*)d_in[7];
    float* out = (float*)d_out;

    unsigned short* xlb = (unsigned short*)d_ws;             // N*512 bf16
    unsigned short* xrb = xlb + (size_t)N_NODES * HC;        // N*512 bf16
    unsigned short* WlT = xrb + (size_t)N_NODES * HC;        // 512*128 bf16
    unsigned short* WrT = WlT + HC * IN_CH;
    unsigned short* WeT = WrT + HC * IN_CH;
    unsigned short* eab = WeT + HC * IN_CH;                  // M_TOT*128 bf16
    float* logits    = (float*)(eab + (size_t)M_TOT * IN_CH); // M_TOT*8 f32
    int* deg         = (int*)(logits + (size_t)M_TOT * 8);
    int* rowptr      = deg + N_NODES;
    int* cursor      = rowptr + N_NODES + 1;
    int* eidx        = cursor + N_NODES;
    int* src_s       = eidx + M_TOT;
    int* dst_s       = src_s + M_TOT;
    int* bsum        = dst_s + M_TOT;
    int* boff        = bsum + NCHUNK;

    const int B = 256;
    hipMemsetAsync(deg, 0, N_NODES * sizeof(int), stream);
    k_deg<<<(E_EDGES + B - 1) / B, B, 0, stream>>>(ei, deg);
    k_scan1<<<NCHUNK, B, 0, stream>>>(deg, bsum);
    k_scan2<<<1, 64, 0, stream>>>(bsum, boff);
    k_scan3<<<NCHUNK, B, 0, stream>>>(deg, boff, rowptr, cursor, eidx, src_s, dst_s);
    k_fill<<<(E_EDGES + B - 1) / B, B, 0, stream>>>(ei, cursor, eidx, src_s, dst_s);
    k_prep<<<((size_t)N_NODES * 64 + B - 1) / B, B, 0, stream>>>(rowptr, eidx, ea, eab);
    k_trans3<<<dim3((HC * IN_CH + B - 1) / B, 3), B, 0, stream>>>(Wl, Wr, We, WlT, WrT, WeT);
    k_gemm2<<<dim3((N_NODES + 63) / 64, 4), B, 0, stream>>>(x, WlT, WrT, xlb, xrb, N_NODES);
    k_fused<<<(M_TOT + 63) / 64, B, 0, stream>>>(src_s, dst_s, rowptr, eab, WeT,
                                                 xlb, xrb, att, bias, logits, out);
    k_cleanup<<<((size_t)N_NODES * 64 + B - 1) / B, B, 0, stream>>>(rowptr, src_s, logits,
                                                                    xlb, bias, out);
}

// Round 10
// 247.670 us; speedup vs baseline: 1.1686x; 1.0444x over previous
//
#include <hip/hip_runtime.h>

#define N_NODES 20000
#define E_EDGES 160000
#define IN_CH 128
#define H_HEADS 8
#define C_CH 64
#define HC 512
#define M_TOT (E_EDGES + N_NODES)
#define NEG_SLOPE 0.2f
#define NCHUNK ((N_NODES + 255) / 256)

typedef __attribute__((ext_vector_type(8))) short bf16x8;
typedef __attribute__((ext_vector_type(4))) short bf16x4;
typedef __attribute__((ext_vector_type(4))) float f32x4;

__device__ __forceinline__ unsigned short f2bf(float f) {
    unsigned u = __float_as_uint(f);
    unsigned r = (u + 0x7FFFu + ((u >> 16) & 1u)) >> 16;   // RNE
    return (unsigned short)r;
}
__device__ __forceinline__ unsigned short f2bf_trunc(float f) {
    return (unsigned short)(__float_as_uint(f) >> 16);     // 1-inst truncate (xeT only)
}
__device__ __forceinline__ float bf2f(unsigned short s) {
    return __uint_as_float((unsigned)s << 16);
}
__device__ __forceinline__ float bfx(const bf16x8& v0, const bf16x8& v1, int idx) {
    return bf2f((unsigned short)((idx < 8) ? v0[idx] : v1[idx - 8]));
}

#define GLOAD_LDS16(gsrc, ldst) \
    __builtin_amdgcn_global_load_lds((const __attribute__((address_space(1))) void*)(gsrc), \
                                     (__attribute__((address_space(3))) void*)(ldst), 16, 0, 0)

// ---------------- CSR build ----------------
__global__ void k_deg(const int* __restrict__ ei, int* __restrict__ deg) {
    int e = blockIdx.x * blockDim.x + threadIdx.x;
    if (e >= E_EDGES) return;
    atomicAdd(&deg[ei[E_EDGES + e]], 1);
}

__global__ void k_scan1(const int* __restrict__ deg, int* __restrict__ bsum) {
    __shared__ int red[256];
    int tid = threadIdx.x;
    int i = blockIdx.x * 256 + tid;
    red[tid] = (i < N_NODES) ? deg[i] + 1 : 0;
    __syncthreads();
    for (int off = 128; off > 0; off >>= 1) {
        if (tid < off) red[tid] += red[tid + off];
        __syncthreads();
    }
    if (tid == 0) bsum[blockIdx.x] = red[0];
}

__global__ void k_scan2(const int* __restrict__ bsum, int* __restrict__ boff) {
    if (threadIdx.x == 0) {
        int run = 0;
        for (int b = 0; b < NCHUNK; ++b) { boff[b] = run; run += bsum[b]; }
    }
}

__global__ void k_scan3(const int* __restrict__ deg, const int* __restrict__ boff,
                        int* __restrict__ rowptr, int* __restrict__ cursor,
                        int4* __restrict__ edat) {
    __shared__ int buf[256];
    int tid = threadIdx.x;
    int i = blockIdx.x * 256 + tid;
    int v = (i < N_NODES) ? deg[i] + 1 : 0;
    buf[tid] = v;
    __syncthreads();
    for (int off = 1; off < 256; off <<= 1) {
        int tv = (tid >= off) ? buf[tid - off] : 0;
        __syncthreads();
        buf[tid] += tv;
        __syncthreads();
    }
    if (i < N_NODES) {
        int excl = boff[blockIdx.x] + buf[tid] - v;
        rowptr[i] = excl;
        edat[excl] = make_int4(E_EDGES + i, i, i, 0);   // self-loop in slot 0
        cursor[i] = excl + 1;
        if (i == N_NODES - 1) rowptr[N_NODES] = excl + v;   // == M_TOT
    }
}

__global__ void k_fill(const int* __restrict__ ei, int* __restrict__ cursor,
                       int4* __restrict__ edat) {
    int e = blockIdx.x * blockDim.x + threadIdx.x;
    if (e >= E_EDGES) return;
    int d = ei[E_EDGES + e];
    int slot = atomicAdd(&cursor[d], 1);
    edat[slot] = make_int4(e, ei[e], d, 0);
}

// ---------------- k_prep: eab[p][128] bf16 in CSR order + self-loop mean ----------------
__global__ void k_prep(const int* __restrict__ rowptr, const int4* __restrict__ edat,
                       const float* __restrict__ ea, unsigned short* __restrict__ eab) {
    int node = (blockIdx.x * blockDim.x + threadIdx.x) >> 6;
    int lane = threadIdx.x & 63;
    if (node >= N_NODES) return;
    int beg = rowptr[node], end = rowptr[node + 1];
    int cnt = end - beg - 1;
    float s0 = 0.f, s1 = 0.f;
    if (beg + 1 < end) {
        const float* p_nxt = ea + (size_t)edat[beg + 1].x * 128 + lane;
        for (int p = beg + 1; p < end; ++p) {
            const float* cur = p_nxt;
            if (p + 1 < end) p_nxt = ea + (size_t)edat[p + 1].x * 128 + lane;
            float v0 = cur[0], v1 = cur[64];
            s0 += v0; s1 += v1;
            eab[(size_t)p * 128 + lane] = f2bf(v0);
            eab[(size_t)p * 128 + 64 + lane] = f2bf(v1);
        }
    }
    float inv = 1.f / fmaxf((float)cnt, 1.f);
    eab[(size_t)beg * 128 + lane] = f2bf(s0 * inv);
    eab[(size_t)beg * 128 + 64 + lane] = f2bf(s1 * inv);
}

// ---------------- weight transpose + bf16 (all three) ----------------
__global__ void k_trans3(const float* __restrict__ Wl, const float* __restrict__ Wr,
                         const float* __restrict__ We,
                         unsigned short* __restrict__ WlT, unsigned short* __restrict__ WrT,
                         unsigned short* __restrict__ WeT) {
    int idx = blockIdx.x * blockDim.x + threadIdx.x;
    if (idx >= HC * IN_CH) return;
    int m = blockIdx.y;
    const float* W = (m == 0) ? Wl : (m == 1) ? Wr : We;
    unsigned short* WT = (m == 0) ? WlT : (m == 1) ? WrT : WeT;
    int n = idx >> 7, k = idx & 127;
    WT[idx] = f2bf(W[(size_t)k * HC + n]);
}

// ---------------- merged dual MFMA GEMM ----------------
__global__ void k_gemm2(const float* __restrict__ A,
                        const unsigned short* __restrict__ WlT,
                        const unsigned short* __restrict__ WrT,
                        unsigned short* __restrict__ xlb, unsigned short* __restrict__ xrb,
                        int M) {
    __shared__ short As[64 * 128];
    int row0 = blockIdx.x * 64;
    int sel = blockIdx.y >> 1;
    const unsigned short* BT = sel ? WrT : WlT;
    unsigned short* Cb = sel ? xrb : xlb;
    int t = threadIdx.x;
    {
        int row = t >> 2, c0 = (t & 3) * 32;
        int gr = row0 + row;
        int sw = (row & 7) << 4;
        const float* src = A + (size_t)gr * 128 + c0;
        #pragma unroll
        for (int i = 0; i < 4; ++i) {
            bf16x8 v;
            if (gr < M) {
                const float4* p = (const float4*)(src + i * 8);
                float4 f0 = p[0], f1 = p[1];
                v[0] = f2bf(f0.x); v[1] = f2bf(f0.y); v[2] = f2bf(f0.z); v[3] = f2bf(f0.w);
                v[4] = f2bf(f1.x); v[5] = f2bf(f1.y); v[6] = f2bf(f1.z); v[7] = f2bf(f1.w);
            } else {
                #pragma unroll
                for (int j = 0; j < 8; ++j) v[j] = 0;
            }
            int off = row * 256 + (((c0 + i * 8) * 2) ^ sw);
            *(bf16x8*)((char*)As + off) = v;
        }
    }
    __syncthreads();

    int w = t >> 6, l = t & 63;
    int lr = l & 15, lk = l >> 4;
    int col0 = (blockIdx.y & 1) * 256 + w * 64;

    f32x4 acc[4][4];
    #pragma unroll
    for (int mi = 0; mi < 4; ++mi)
        #pragma unroll
        for (int fj = 0; fj < 4; ++fj)
            #pragma unroll
            for (int q = 0; q < 4; ++q) acc[mi][fj][q] = 0.f;

    #pragma unroll
    for (int k0 = 0; k0 < 4; ++k0) {
        bf16x8 a4[4];
        #pragma unroll
        for (int mi = 0; mi < 4; ++mi) {
            int row = mi * 16 + lr;
            int off = row * 256 + ((k0 * 64 + lk * 16) ^ ((row & 7) << 4));
            a4[mi] = *(const bf16x8*)((const char*)As + off);
        }
        #pragma unroll
        for (int fj = 0; fj < 4; ++fj) {
            bf16x8 b = *(const bf16x8*)(BT + (size_t)(col0 + fj * 16 + lr) * 128 + k0 * 32 + lk * 8);
            #pragma unroll
            for (int mi = 0; mi < 4; ++mi)
                acc[mi][fj] = __builtin_amdgcn_mfma_f32_16x16x32_bf16(a4[mi], b, acc[mi][fj], 0, 0, 0);
        }
    }
    #pragma unroll
    for (int mi = 0; mi < 4; ++mi) {
        #pragma unroll
        for (int reg = 0; reg < 4; ++reg) {
            int r = row0 + mi * 16 + lk * 4 + reg;
            if (r < M) {
                unsigned short* cp = Cb + (size_t)r * 512 + col0 + lr;
                #pragma unroll
                for (int fj = 0; fj < 4; ++fj) cp[fj * 16] = f2bf(acc[mi][fj][reg]);
            }
        }
    }
}

// ---------------- fused: head-group-split edge GEMM + scoring + interior agg ----------------
// grid.y = 2: block y handles heads 4y..4y+3 (one head per wave).
#define PREF(R, CB, SLOT) { \
    int s_ = s_src[R], d_ = s_dst[R]; \
    const bf16x8* xp_ = (const bf16x8*)(xlb + (size_t)s_ * 512 + (CB) + q * 16); \
    pa0[SLOT] = xp_[0]; pa1[SLOT] = xp_[1]; \
    const bf16x8* rp_ = (const bf16x8*)(xrb + (size_t)d_ * 512 + (CB) + q * 16); \
    pb0[SLOT] = rp_[0]; pb1[SLOT] = rp_[1]; }

__global__ void k_fused(const int4* __restrict__ edat, const int* __restrict__ rowptr,
                        const unsigned short* __restrict__ eab,
                        const unsigned short* __restrict__ WeT,
                        const unsigned short* __restrict__ xlb,
                        const unsigned short* __restrict__ xrb,
                        const float* __restrict__ att, const float* __restrict__ bias,
                        float* __restrict__ lq, float* __restrict__ out) {
    __shared__ short As[64 * 128];
    __shared__ unsigned short xeT[4][16][72];   // bf16, 144B row stride
    __shared__ float att_s[256];
    __shared__ float lg[64][4];
    __shared__ int s_src[64], s_dst[64];
    __shared__ int own_node[64], own_beg[64], own_len[64];
    __shared__ int n_own;
    int row0 = blockIdx.x * 64;
    int y = blockIdx.y;            // head group
    int t = threadIdx.x;

    if (t == 0) n_own = 0;
    __syncthreads();

    // async staged A-tile: contiguous bf16 rows of eab, inverse-swizzled source
    {
        int l = t & 63;
        int c_base = (t >> 6) * 4;
        #pragma unroll
        for (int i = 0; i < 4; ++i) {
            int c = c_base + i;
            int row_local = c * 4 + (l >> 4);
            int grow = row0 + row_local;
            if (grow > M_TOT - 1) grow = M_TOT - 1;
            int chunk = (l & 15) ^ (row_local & 7);
            const char* src = (const char*)eab + (size_t)grow * 256 + chunk * 16;
            char* dst = (char*)As + c * 1024;
            GLOAD_LDS16(src, dst);
        }
    }

    if (t < 64) {
        int p = row0 + t;
        int s = 0, d = 0;
        if (p < M_TOT) {
            int4 v = edat[p];
            s = v.y; d = v.z;
            int pb = rowptr[d], pe = rowptr[d + 1];
            if (pb == p && pe <= row0 + 64) {          // interior segment, first row
                int idx = atomicAdd(&n_own, 1);
                own_node[idx] = d; own_beg[idx] = t; own_len[idx] = pe - pb;
            }
        }
        s_src[t] = s; s_dst[t] = d;
    }
    att_s[t & 255] = att[y * 256 + (t & 255)];

    asm volatile("s_waitcnt vmcnt(0)");
    __syncthreads();

    int w = t >> 6, l = t & 63;
    int lr = l & 15, lk = l >> 4;
    int eloc = l >> 2, q = l & 3;   // epilogue: 4 lanes per edge
    int h = y * 4 + w;              // this wave's head
    int cb = h * 64;

    bf16x8 pa0[2], pa1[2], pb0[2], pb1[2];
    f32x4 acc[4][4];

    PREF(eloc, cb, 0);

    #pragma unroll
    for (int mi = 0; mi < 4; ++mi)
        #pragma unroll
        for (int fj = 0; fj < 4; ++fj)
            #pragma unroll
            for (int qq = 0; qq < 4; ++qq) acc[mi][fj][qq] = 0.f;

    #pragma unroll
    for (int k0 = 0; k0 < 4; ++k0) {
        bf16x8 a4[4];
        #pragma unroll
        for (int mi = 0; mi < 4; ++mi) {
            int row = mi * 16 + lr;
            int off = row * 256 + ((k0 * 64 + lk * 16) ^ ((row & 7) << 4));
            a4[mi] = *(const bf16x8*)((const char*)As + off);
        }
        #pragma unroll
        for (int fj = 0; fj < 4; ++fj) {
            bf16x8 b = *(const bf16x8*)(WeT + (size_t)(cb + fj * 16 + lr) * 128 + k0 * 32 + lk * 8);
            #pragma unroll
            for (int mi = 0; mi < 4; ++mi)
                acc[mi][fj] = __builtin_amdgcn_mfma_f32_16x16x32_bf16(a4[mi], b, acc[mi][fj], 0, 0, 0);
        }
    }

    #pragma unroll
    for (int mi = 0; mi < 4; ++mi) {
        if (mi < 3) { PREF(mi * 16 + 16 + eloc, cb, (mi + 1) & 1); }

        #pragma unroll
        for (int fj = 0; fj < 4; ++fj)
            #pragma unroll
            for (int reg = 0; reg < 4; ++reg)
                xeT[w][lk * 4 + reg][fj * 16 + lr] = f2bf_trunc(acc[mi][fj][reg]);

        const bf16x8 ca0 = pa0[mi & 1], ca1 = pa1[mi & 1];
        const bf16x8 cb0v = pb0[mi & 1], cb1v = pb1[mi & 1];

        bf16x8 x0 = *(const bf16x8*)&xeT[w][eloc][q * 16];
        bf16x8 x1 = *(const bf16x8*)&xeT[w][eloc][q * 16 + 8];

        float sum = 0.f;
        #pragma unroll
        for (int sg = 0; sg < 4; ++sg) {
            float4 av = *(const float4*)&att_s[w * 64 + q * 16 + sg * 4];
            float v0 = bfx(x0, x1, sg * 4 + 0) + bfx(ca0, ca1, sg * 4 + 0) + bfx(cb0v, cb1v, sg * 4 + 0);
            float v1 = bfx(x0, x1, sg * 4 + 1) + bfx(ca0, ca1, sg * 4 + 1) + bfx(cb0v, cb1v, sg * 4 + 1);
            float v2 = bfx(x0, x1, sg * 4 + 2) + bfx(ca0, ca1, sg * 4 + 2) + bfx(cb0v, cb1v, sg * 4 + 2);
            float v3 = bfx(x0, x1, sg * 4 + 3) + bfx(ca0, ca1, sg * 4 + 3) + bfx(cb0v, cb1v, sg * 4 + 3);
            v0 = (v0 > 0.f) ? v0 : v0 * NEG_SLOPE;
            v1 = (v1 > 0.f) ? v1 : v1 * NEG_SLOPE;
            v2 = (v2 > 0.f) ? v2 : v2 * NEG_SLOPE;
            v3 = (v3 > 0.f) ? v3 : v3 * NEG_SLOPE;
            sum = fmaf(av.x, v0, sum);
            sum = fmaf(av.y, v1, sum);
            sum = fmaf(av.z, v2, sum);
            sum = fmaf(av.w, v3, sum);
        }
        sum += __shfl_xor(sum, 1, 64);
        sum += __shfl_xor(sum, 2, 64);
        if (q == 0) lg[mi * 16 + eloc][w] = sum;
    }
    __syncthreads();

    // coalesced planar logits write: lq[y][p][4]
    if (t < 64) {
        int p = row0 + t;
        if (p < M_TOT) {
            const float4* lr4 = (const float4*)&lg[t][0];
            *(float4*)(lq + ((size_t)y * M_TOT + p) * 4) = lr4[0];
        }
    }

    // interior softmax + aggregation: this block's 4 heads = channels y*256..y*256+255
    {
        int lane = t & 63;
        int hl = lane >> 4;              // head-local 0..3
        int coff = y * 256 + lane * 4;   // 4 channels per lane
        for (int o = w; o < n_own; o += 4) {
            int d = own_node[o], rb = own_beg[o], len = own_len[o];
            float m = -3.4e38f;
            for (int j = 0; j < len; ++j) m = fmaxf(m, lg[rb + j][hl]);
            float den = 0.f;
            for (int j = 0; j < len; ++j) den += __expf(lg[rb + j][hl] - m);
            float rden = 1.f / den;
            float ac[4] = {};
            bf16x4 v_nxt = *(const bf16x4*)(xlb + (size_t)s_src[rb] * 512 + coff);
            for (int j = 0; j < len; ++j) {
                bf16x4 v = v_nxt;
                if (j + 1 < len)
                    v_nxt = *(const bf16x4*)(xlb + (size_t)s_src[rb + j + 1] * 512 + coff);
                float alpha = __expf(lg[rb + j][hl] - m) * rden;
                #pragma unroll
                for (int jj = 0; jj < 4; ++jj) ac[jj] = fmaf(alpha, bf2f((unsigned short)v[jj]), ac[jj]);
            }
            const float4* bp = (const float4*)(bias + coff);
            float4 bv = bp[0];
            float4 r0 = { ac[0] + bv.x, ac[1] + bv.y, ac[2] + bv.z, ac[3] + bv.w };
            *(float4*)(out + (size_t)d * 512 + coff) = r0;
        }
    }
}

// ---------------- cleanup: boundary segments only ----------------
__global__ void k_cleanup(const int* __restrict__ rowptr, const int4* __restrict__ edat,
                          const float* __restrict__ lq,
                          const unsigned short* __restrict__ xlb, const float* __restrict__ bias,
                          float* __restrict__ out) {
    int node = (blockIdx.x * blockDim.x + threadIdx.x) >> 6;
    int lane = threadIdx.x & 63;
    if (node >= N_NODES) return;
    int beg = rowptr[node], end = rowptr[node + 1];
    if ((beg >> 6) == ((end - 1) >> 6)) return;   // interior: handled in k_fused
    int h = lane >> 3;
    const float* lp = lq + (size_t)(h >> 2) * M_TOT * 4 + (h & 3);

    float m = -3.4e38f;
    for (int p = beg; p < end; ++p) m = fmaxf(m, lp[(size_t)p * 4]);
    float den = 0.f;
    for (int p = beg; p < end; ++p) den += __expf(lp[(size_t)p * 4] - m);
    float rden = 1.f / den;

    float acc[8] = {};
    bf16x8 v_nxt = *(const bf16x8*)(xlb + (size_t)edat[beg].y * 512 + lane * 8);
    for (int p = beg; p < end; ++p) {
        bf16x8 v = v_nxt;
        float lgv = lp[(size_t)p * 4];
        if (p + 1 < end)
            v_nxt = *(const bf16x8*)(xlb + (size_t)edat[p + 1].y * 512 + lane * 8);
        float alpha = __expf(lgv - m) * rden;
        #pragma unroll
        for (int j = 0; j < 8; ++j) acc[j] = fmaf(alpha, bf2f((unsigned short)v[j]), acc[j]);
    }
    float4* op = (float4*)(out + (size_t)node * 512 + lane * 8);
    const float4* bp = (const float4*)(bias + lane * 8);
    float4 bv0 = bp[0], bv1 = bp[1];
    float4 r0 = { acc[0] + bv0.x, acc[1] + bv0.y, acc[2] + bv0.z, acc[3] + bv0.w };
    float4 r1 = { acc[4] + bv1.x, acc[5] + bv1.y, acc[6] + bv1.z, acc[7] + bv1.w };
    op[0] = r0; op[1] = r1;
}

extern "C" void kernel_launch(void* const* d_in, const int* in_sizes, int n_in,
                              void* d_out, int out_size, void* d_ws, size_t ws_size,
                              hipStream_t stream) {
    const float* x    = (const float*)d_in[0];
    const int*   ei   = (const int*)d_in[1];
    const float* ea   = (const float*)d_in[2];
    const float* Wl   = (const float*)d_in[3];
    const float* Wr   = (const float*)d_in[4];
    const float* We   = (const float*)d_in[5];
    const float* att  = (const float*)d_in[6];
    const float* bias = (const float*)d_in[7];
    float* out = (float*)d_out;

    unsigned short* xlb = (unsigned short*)d_ws;             // N*512 bf16
    unsigned short* xrb = xlb + (size_t)N_NODES * HC;        // N*512 bf16
    unsigned short* WlT = xrb + (size_t)N_NODES * HC;        // 512*128 bf16
    unsigned short* WrT = WlT + HC * IN_CH;
    unsigned short* WeT = WrT + HC * IN_CH;
    unsigned short* eab = WeT + HC * IN_CH;                  // M_TOT*128 bf16
    float* lq        = (float*)(eab + (size_t)M_TOT * IN_CH); // 2 planes * M_TOT * 4 f32
    int4* edat       = (int4*)(lq + (size_t)2 * M_TOT * 4);  // M_TOT int4 (16B aligned)
    int* deg         = (int*)(edat + M_TOT);
    int* rowptr      = deg + N_NODES;
    int* cursor      = rowptr + N_NODES + 1;
    int* bsum        = cursor + N_NODES;
    int* boff        = bsum + NCHUNK;

    const int B = 256;
    hipMemsetAsync(deg, 0, N_NODES * sizeof(int), stream);
    k_deg<<<(E_EDGES + B - 1) / B, B, 0, stream>>>(ei, deg);
    k_scan1<<<NCHUNK, B, 0, stream>>>(deg, bsum);
    k_scan2<<<1, 64, 0, stream>>>(bsum, boff);
    k_scan3<<<NCHUNK, B, 0, stream>>>(deg, boff, rowptr, cursor, edat);
    k_fill<<<(E_EDGES + B - 1) / B, B, 0, stream>>>(ei, cursor, edat);
    k_prep<<<((size_t)N_NODES * 64 + B - 1) / B, B, 0, stream>>>(rowptr, edat, ea, eab);
    k_trans3<<<dim3((HC * IN_CH + B - 1) / B, 3), B, 0, stream>>>(Wl, Wr, We, WlT, WrT, WeT);
    k_gemm2<<<dim3((N_NODES + 63) / 64, 4), B, 0, stream>>>(x, WlT, WrT, xlb, xrb, N_NODES);
    k_fused<<<dim3((M_TOT + 63) / 64, 2), B, 0, stream>>>(edat, rowptr, eab, WeT,
                                                          xlb, xrb, att, bias, lq, out);
    k_cleanup<<<((size_t)N_NODES * 64 + B - 1) / B, B, 0, stream>>>(rowptr, edat, lq,
                                                                    xlb, bias, out);
}

// Round 11
// 232.507 us; speedup vs baseline: 1.2448x; 1.0652x over previous
//
#include <hip/hip_runtime.h>

#define N_NODES 20000
#define E_EDGES 160000
#define IN_CH 128
#define H_HEADS 8
#define C_CH 64
#define HC 512
#define M_TOT (E_EDGES + N_NODES)
#define NEG_SLOPE 0.2f
#define NCHUNK ((N_NODES + 255) / 256)

typedef __attribute__((ext_vector_type(8))) short bf16x8;
typedef __attribute__((ext_vector_type(4))) float f32x4;

__device__ __forceinline__ unsigned short f2bf(float f) {
    unsigned u = __float_as_uint(f);
    unsigned r = (u + 0x7FFFu + ((u >> 16) & 1u)) >> 16;   // RNE
    return (unsigned short)r;
}
__device__ __forceinline__ unsigned short f2bf_trunc(float f) {
    return (unsigned short)(__float_as_uint(f) >> 16);     // 1-inst truncate (xeT only)
}
__device__ __forceinline__ float bf2f(unsigned short s) {
    return __uint_as_float((unsigned)s << 16);
}
__device__ __forceinline__ float bfx(const bf16x8& v0, const bf16x8& v1, int idx) {
    return bf2f((unsigned short)((idx < 8) ? v0[idx] : v1[idx - 8]));
}

#define GLOAD_LDS16(gsrc, ldst) \
    __builtin_amdgcn_global_load_lds((const __attribute__((address_space(1))) void*)(gsrc), \
                                     (__attribute__((address_space(3))) void*)(ldst), 16, 0, 0)

// ---------------- CSR build ----------------
__global__ void k_deg(const int* __restrict__ ei, int* __restrict__ deg) {
    int e = blockIdx.x * blockDim.x + threadIdx.x;
    if (e >= E_EDGES) return;
    atomicAdd(&deg[ei[E_EDGES + e]], 1);
}

__global__ void k_scan1(const int* __restrict__ deg, int* __restrict__ bsum) {
    __shared__ int red[256];
    int tid = threadIdx.x;
    int i = blockIdx.x * 256 + tid;
    red[tid] = (i < N_NODES) ? deg[i] + 1 : 0;
    __syncthreads();
    for (int off = 128; off > 0; off >>= 1) {
        if (tid < off) red[tid] += red[tid + off];
        __syncthreads();
    }
    if (tid == 0) bsum[blockIdx.x] = red[0];
}

__global__ void k_scan2(const int* __restrict__ bsum, int* __restrict__ boff) {
    if (threadIdx.x == 0) {
        int run = 0;
        for (int b = 0; b < NCHUNK; ++b) { boff[b] = run; run += bsum[b]; }
    }
}

__global__ void k_scan3(const int* __restrict__ deg, const int* __restrict__ boff,
                        int* __restrict__ rowptr, int* __restrict__ cursor,
                        int4* __restrict__ edat) {
    __shared__ int buf[256];
    int tid = threadIdx.x;
    int i = blockIdx.x * 256 + tid;
    int v = (i < N_NODES) ? deg[i] + 1 : 0;
    buf[tid] = v;
    __syncthreads();
    for (int off = 1; off < 256; off <<= 1) {
        int tv = (tid >= off) ? buf[tid - off] : 0;
        __syncthreads();
        buf[tid] += tv;
        __syncthreads();
    }
    if (i < N_NODES) {
        int excl = boff[blockIdx.x] + buf[tid] - v;
        rowptr[i] = excl;
        edat[excl] = make_int4(E_EDGES + i, i, i, 0);   // self-loop in slot 0
        cursor[i] = excl + 1;
        if (i == N_NODES - 1) rowptr[N_NODES] = excl + v;   // == M_TOT
    }
}

__global__ void k_fill(const int* __restrict__ ei, int* __restrict__ cursor,
                       int4* __restrict__ edat) {
    int e = blockIdx.x * blockDim.x + threadIdx.x;
    if (e >= E_EDGES) return;
    int d = ei[E_EDGES + e];
    int slot = atomicAdd(&cursor[d], 1);
    edat[slot] = make_int4(e, ei[e], d, 0);
}

// ---------------- k_prep: eab[p][128] bf16 in CSR order + self-loop mean ----------------
__global__ void k_prep(const int* __restrict__ rowptr, const int4* __restrict__ edat,
                       const float* __restrict__ ea, unsigned short* __restrict__ eab) {
    int node = (blockIdx.x * blockDim.x + threadIdx.x) >> 6;
    int lane = threadIdx.x & 63;
    if (node >= N_NODES) return;
    int beg = rowptr[node], end = rowptr[node + 1];
    int cnt = end - beg - 1;
    float s0 = 0.f, s1 = 0.f;
    if (beg + 1 < end) {
        const float* p_nxt = ea + (size_t)edat[beg + 1].x * 128 + lane;
        for (int p = beg + 1; p < end; ++p) {
            const float* cur = p_nxt;
            if (p + 1 < end) p_nxt = ea + (size_t)edat[p + 1].x * 128 + lane;
            float v0 = cur[0], v1 = cur[64];
            s0 += v0; s1 += v1;
            eab[(size_t)p * 128 + lane] = f2bf(v0);
            eab[(size_t)p * 128 + 64 + lane] = f2bf(v1);
        }
    }
    float inv = 1.f / fmaxf((float)cnt, 1.f);
    eab[(size_t)beg * 128 + lane] = f2bf(s0 * inv);
    eab[(size_t)beg * 128 + 64 + lane] = f2bf(s1 * inv);
}

// ---------------- weight transpose + bf16 (all three) ----------------
__global__ void k_trans3(const float* __restrict__ Wl, const float* __restrict__ Wr,
                         const float* __restrict__ We,
                         unsigned short* __restrict__ WlT, unsigned short* __restrict__ WrT,
                         unsigned short* __restrict__ WeT) {
    int idx = blockIdx.x * blockDim.x + threadIdx.x;
    if (idx >= HC * IN_CH) return;
    int m = blockIdx.y;
    const float* W = (m == 0) ? Wl : (m == 1) ? Wr : We;
    unsigned short* WT = (m == 0) ? WlT : (m == 1) ? WrT : WeT;
    int n = idx >> 7, k = idx & 127;
    WT[idx] = f2bf(W[(size_t)k * HC + n]);
}

// ---------------- merged dual MFMA GEMM ----------------
__global__ void k_gemm2(const float* __restrict__ A,
                        const unsigned short* __restrict__ WlT,
                        const unsigned short* __restrict__ WrT,
                        unsigned short* __restrict__ xlb, unsigned short* __restrict__ xrb,
                        int M) {
    __shared__ short As[64 * 128];
    int row0 = blockIdx.x * 64;
    int sel = blockIdx.y >> 1;
    const unsigned short* BT = sel ? WrT : WlT;
    unsigned short* Cb = sel ? xrb : xlb;
    int t = threadIdx.x;
    {
        int row = t >> 2, c0 = (t & 3) * 32;
        int gr = row0 + row;
        int sw = (row & 7) << 4;
        const float* src = A + (size_t)gr * 128 + c0;
        #pragma unroll
        for (int i = 0; i < 4; ++i) {
            bf16x8 v;
            if (gr < M) {
                const float4* p = (const float4*)(src + i * 8);
                float4 f0 = p[0], f1 = p[1];
                v[0] = f2bf(f0.x); v[1] = f2bf(f0.y); v[2] = f2bf(f0.z); v[3] = f2bf(f0.w);
                v[4] = f2bf(f1.x); v[5] = f2bf(f1.y); v[6] = f2bf(f1.z); v[7] = f2bf(f1.w);
            } else {
                #pragma unroll
                for (int j = 0; j < 8; ++j) v[j] = 0;
            }
            int off = row * 256 + (((c0 + i * 8) * 2) ^ sw);
            *(bf16x8*)((char*)As + off) = v;
        }
    }
    __syncthreads();

    int w = t >> 6, l = t & 63;
    int lr = l & 15, lk = l >> 4;
    int col0 = (blockIdx.y & 1) * 256 + w * 64;

    f32x4 acc[4][4];
    #pragma unroll
    for (int mi = 0; mi < 4; ++mi)
        #pragma unroll
        for (int fj = 0; fj < 4; ++fj)
            #pragma unroll
            for (int q = 0; q < 4; ++q) acc[mi][fj][q] = 0.f;

    #pragma unroll
    for (int k0 = 0; k0 < 4; ++k0) {
        bf16x8 a4[4];
        #pragma unroll
        for (int mi = 0; mi < 4; ++mi) {
            int row = mi * 16 + lr;
            int off = row * 256 + ((k0 * 64 + lk * 16) ^ ((row & 7) << 4));
            a4[mi] = *(const bf16x8*)((const char*)As + off);
        }
        #pragma unroll
        for (int fj = 0; fj < 4; ++fj) {
            bf16x8 b = *(const bf16x8*)(BT + (size_t)(col0 + fj * 16 + lr) * 128 + k0 * 32 + lk * 8);
            #pragma unroll
            for (int mi = 0; mi < 4; ++mi)
                acc[mi][fj] = __builtin_amdgcn_mfma_f32_16x16x32_bf16(a4[mi], b, acc[mi][fj], 0, 0, 0);
        }
    }
    #pragma unroll
    for (int mi = 0; mi < 4; ++mi) {
        #pragma unroll
        for (int reg = 0; reg < 4; ++reg) {
            int r = row0 + mi * 16 + lk * 4 + reg;
            if (r < M) {
                unsigned short* cp = Cb + (size_t)r * 512 + col0 + lr;
                #pragma unroll
                for (int fj = 0; fj < 4; ++fj) cp[fj * 16] = f2bf(acc[mi][fj][reg]);
            }
        }
    }
}

// ---------------- fused: 8-wave block, one head per wave, eab staged ONCE ----------------
#define PREF(R, CB, SLOT) { \
    int s_ = s_src[R], d_ = s_dst[R]; \
    const bf16x8* xp_ = (const bf16x8*)(xlb + (size_t)s_ * 512 + (CB) + q * 16); \
    pa0[SLOT] = xp_[0]; pa1[SLOT] = xp_[1]; \
    const bf16x8* rp_ = (const bf16x8*)(xrb + (size_t)d_ * 512 + (CB) + q * 16); \
    pb0[SLOT] = rp_[0]; pb1[SLOT] = rp_[1]; }

__global__ __launch_bounds__(512, 2)
void k_fused(const int4* __restrict__ edat, const int* __restrict__ rowptr,
             const unsigned short* __restrict__ eab,
             const unsigned short* __restrict__ WeT,
             const unsigned short* __restrict__ xlb,
             const unsigned short* __restrict__ xrb,
             const float* __restrict__ att, const float* __restrict__ bias,
             float* __restrict__ logits, float* __restrict__ out) {
    __shared__ short As[64 * 128];
    __shared__ unsigned short xeT[8][16][72];   // bf16, 144B row stride
    __shared__ float att_s[512];
    __shared__ float lg[64][8];
    __shared__ int s_src[64], s_dst[64];
    __shared__ int own_node[64], own_beg[64], own_len[64];
    __shared__ int n_own;
    int row0 = blockIdx.x * 64;
    int t = threadIdx.x;

    if (t == 0) n_own = 0;
    __syncthreads();

    // async staged A-tile (once): contiguous bf16 rows of eab, inverse-swizzled source
    {
        int l = t & 63;
        int c_base = (t >> 6) * 2;
        #pragma unroll
        for (int i = 0; i < 2; ++i) {
            int c = c_base + i;
            int row_local = c * 4 + (l >> 4);
            int grow = row0 + row_local;
            if (grow > M_TOT - 1) grow = M_TOT - 1;
            int chunk = (l & 15) ^ (row_local & 7);
            const char* src = (const char*)eab + (size_t)grow * 256 + chunk * 16;
            char* dst = (char*)As + c * 1024;
            GLOAD_LDS16(src, dst);
        }
    }

    if (t < 64) {
        int p = row0 + t;
        int s = 0, d = 0;
        if (p < M_TOT) {
            int4 v = edat[p];
            s = v.y; d = v.z;
            int pb = rowptr[d], pe = rowptr[d + 1];
            if (pb == p && pe <= row0 + 64) {          // interior segment, first row
                int idx = atomicAdd(&n_own, 1);
                own_node[idx] = d; own_beg[idx] = t; own_len[idx] = pe - pb;
            }
        }
        s_src[t] = s; s_dst[t] = d;
    }
    att_s[t] = att[t];

    asm volatile("s_waitcnt vmcnt(0)");
    __syncthreads();

    int w = t >> 6, l = t & 63;          // w = head (0..7)
    int lr = l & 15, lk = l >> 4;
    int eloc = l >> 2, q = l & 3;        // epilogue: 4 lanes per edge
    int cb = w * 64;

    bf16x8 pa0[2], pa1[2], pb0[2], pb1[2];
    f32x4 acc[4][4];

    PREF(eloc, cb, 0);

    #pragma unroll
    for (int mi = 0; mi < 4; ++mi)
        #pragma unroll
        for (int fj = 0; fj < 4; ++fj)
            #pragma unroll
            for (int qq = 0; qq < 4; ++qq) acc[mi][fj][qq] = 0.f;

    #pragma unroll
    for (int k0 = 0; k0 < 4; ++k0) {
        bf16x8 a4[4];
        #pragma unroll
        for (int mi = 0; mi < 4; ++mi) {
            int row = mi * 16 + lr;
            int off = row * 256 + ((k0 * 64 + lk * 16) ^ ((row & 7) << 4));
            a4[mi] = *(const bf16x8*)((const char*)As + off);
        }
        #pragma unroll
        for (int fj = 0; fj < 4; ++fj) {
            bf16x8 b = *(const bf16x8*)(WeT + (size_t)(cb + fj * 16 + lr) * 128 + k0 * 32 + lk * 8);
            #pragma unroll
            for (int mi = 0; mi < 4; ++mi)
                acc[mi][fj] = __builtin_amdgcn_mfma_f32_16x16x32_bf16(a4[mi], b, acc[mi][fj], 0, 0, 0);
        }
    }

    #pragma unroll
    for (int mi = 0; mi < 4; ++mi) {
        if (mi < 3) { PREF(mi * 16 + 16 + eloc, cb, (mi + 1) & 1); }

        #pragma unroll
        for (int fj = 0; fj < 4; ++fj)
            #pragma unroll
            for (int reg = 0; reg < 4; ++reg)
                xeT[w][lk * 4 + reg][fj * 16 + lr] = f2bf_trunc(acc[mi][fj][reg]);

        const bf16x8 ca0 = pa0[mi & 1], ca1 = pa1[mi & 1];
        const bf16x8 cb0v = pb0[mi & 1], cb1v = pb1[mi & 1];

        bf16x8 x0 = *(const bf16x8*)&xeT[w][eloc][q * 16];
        bf16x8 x1 = *(const bf16x8*)&xeT[w][eloc][q * 16 + 8];

        float sum = 0.f;
        #pragma unroll
        for (int sg = 0; sg < 4; ++sg) {
            float4 av = *(const float4*)&att_s[cb + q * 16 + sg * 4];
            float v0 = bfx(x0, x1, sg * 4 + 0) + bfx(ca0, ca1, sg * 4 + 0) + bfx(cb0v, cb1v, sg * 4 + 0);
            float v1 = bfx(x0, x1, sg * 4 + 1) + bfx(ca0, ca1, sg * 4 + 1) + bfx(cb0v, cb1v, sg * 4 + 1);
            float v2 = bfx(x0, x1, sg * 4 + 2) + bfx(ca0, ca1, sg * 4 + 2) + bfx(cb0v, cb1v, sg * 4 + 2);
            float v3 = bfx(x0, x1, sg * 4 + 3) + bfx(ca0, ca1, sg * 4 + 3) + bfx(cb0v, cb1v, sg * 4 + 3);
            v0 = (v0 > 0.f) ? v0 : v0 * NEG_SLOPE;
            v1 = (v1 > 0.f) ? v1 : v1 * NEG_SLOPE;
            v2 = (v2 > 0.f) ? v2 : v2 * NEG_SLOPE;
            v3 = (v3 > 0.f) ? v3 : v3 * NEG_SLOPE;
            sum = fmaf(av.x, v0, sum);
            sum = fmaf(av.y, v1, sum);
            sum = fmaf(av.z, v2, sum);
            sum = fmaf(av.w, v3, sum);
        }
        sum += __shfl_xor(sum, 1, 64);
        sum += __shfl_xor(sum, 2, 64);
        if (q == 0) lg[mi * 16 + eloc][w] = sum;
    }
    __syncthreads();

    // coalesced logits write: 64 rows x 8 heads contiguous
    {
        int nval = (M_TOT - row0 < 64 ? M_TOT - row0 : 64) * 8;
        if (t < 256 && t * 2 < nval) {
            const float* lf = (const float*)lg;
            float2 v = { lf[t * 2], lf[t * 2 + 1] };
            *(float2*)(logits + (size_t)row0 * 8 + t * 2) = v;
        }
    }

    // interior softmax + aggregation: wave w handles segments w, w+8, ...
    {
        int lane = t & 63;
        int h = lane >> 3;
        for (int o = w; o < n_own; o += 8) {
            int d = own_node[o], rb = own_beg[o], len = own_len[o];
            float m = -3.4e38f;
            for (int j = 0; j < len; ++j) m = fmaxf(m, lg[rb + j][h]);
            float den = 0.f;
            for (int j = 0; j < len; ++j) den += __expf(lg[rb + j][h] - m);
            float rden = 1.f / den;
            float ac[8] = {};
            bf16x8 v_nxt = *(const bf16x8*)(xlb + (size_t)s_src[rb] * 512 + lane * 8);
            for (int j = 0; j < len; ++j) {
                bf16x8 v = v_nxt;
                if (j + 1 < len)
                    v_nxt = *(const bf16x8*)(xlb + (size_t)s_src[rb + j + 1] * 512 + lane * 8);
                float alpha = __expf(lg[rb + j][h] - m) * rden;
                #pragma unroll
                for (int jj = 0; jj < 8; ++jj) ac[jj] = fmaf(alpha, bf2f((unsigned short)v[jj]), ac[jj]);
            }
            float4* op = (float4*)(out + (size_t)d * 512 + lane * 8);
            const float4* bp = (const float4*)(bias + lane * 8);
            float4 bv0 = bp[0], bv1 = bp[1];
            float4 r0 = { ac[0] + bv0.x, ac[1] + bv0.y, ac[2] + bv0.z, ac[3] + bv0.w };
            float4 r1 = { ac[4] + bv1.x, ac[5] + bv1.y, ac[6] + bv1.z, ac[7] + bv1.w };
            op[0] = r0; op[1] = r1;
        }
    }
}

// ---------------- cleanup: boundary segments only ----------------
__global__ void k_cleanup(const int* __restrict__ rowptr, const int4* __restrict__ edat,
                          const float* __restrict__ logits,
                          const unsigned short* __restrict__ xlb, const float* __restrict__ bias,
                          float* __restrict__ out) {
    int node = (blockIdx.x * blockDim.x + threadIdx.x) >> 6;
    int lane = threadIdx.x & 63;
    if (node >= N_NODES) return;
    int beg = rowptr[node], end = rowptr[node + 1];
    if ((beg >> 6) == ((end - 1) >> 6)) return;   // interior: handled in k_fused
    int h = lane >> 3;

    float m = -3.4e38f;
    for (int p = beg; p < end; ++p) m = fmaxf(m, logits[(size_t)p * 8 + h]);
    float den = 0.f;
    for (int p = beg; p < end; ++p) den += __expf(logits[(size_t)p * 8 + h] - m);
    float rden = 1.f / den;

    float acc[8] = {};
    bf16x8 v_nxt = *(const bf16x8*)(xlb + (size_t)edat[beg].y * 512 + lane * 8);
    for (int p = beg; p < end; ++p) {
        bf16x8 v = v_nxt;
        float lgv = logits[(size_t)p * 8 + h];
        if (p + 1 < end)
            v_nxt = *(const bf16x8*)(xlb + (size_t)edat[p + 1].y * 512 + lane * 8);
        float alpha = __expf(lgv - m) * rden;
        #pragma unroll
        for (int j = 0; j < 8; ++j) acc[j] = fmaf(alpha, bf2f((unsigned short)v[j]), acc[j]);
    }
    float4* op = (float4*)(out + (size_t)node * 512 + lane * 8);
    const float4* bp = (const float4*)(bias + lane * 8);
    float4 bv0 = bp[0], bv1 = bp[1];
    float4 r0 = { acc[0] + bv0.x, acc[1] + bv0.y, acc[2] + bv0.z, acc[3] + bv0.w };
    float4 r1 = { acc[4] + bv1.x, acc[5] + bv1.y, acc[6] + bv1.z, acc[7] + bv1.w };
    op[0] = r0; op[1] = r1;
}

extern "C" void kernel_launch(void* const* d_in, const int* in_sizes, int n_in,
                              void* d_out, int out_size, void* d_ws, size_t ws_size,
                              hipStream_t stream) {
    const float* x    = (const float*)d_in[0];
    const int*   ei   = (const int*)d_in[1];
    const float* ea   = (const float*)d_in[2];
    const float* Wl   = (const float*)d_in[3];
    const float* Wr   = (const float*)d_in[4];
    const float* We   = (const float*)d_in[5];
    const float* att  = (const float*)d_in[6];
    const float* bias = (const float*)d_in[7];
    float* out = (float*)d_out;

    unsigned short* xlb = (unsigned short*)d_ws;             // N*512 bf16
    unsigned short* xrb = xlb + (size_t)N_NODES * HC;        // N*512 bf16
    unsigned short* WlT = xrb + (size_t)N_NODES * HC;        // 512*128 bf16
    unsigned short* WrT = WlT + HC * IN_CH;
    unsigned short* WeT = WrT + HC * IN_CH;
    unsigned short* eab = WeT + HC * IN_CH;                  // M_TOT*128 bf16
    float* logits    = (float*)(eab + (size_t)M_TOT * IN_CH); // M_TOT*8 f32
    int4* edat       = (int4*)(logits + (size_t)M_TOT * 8);  // M_TOT int4
    int* deg         = (int*)(edat + M_TOT);
    int* rowptr      = deg + N_NODES;
    int* cursor      = rowptr + N_NODES + 1;
    int* bsum        = cursor + N_NODES;
    int* boff        = bsum + NCHUNK;

    const int B = 256;
    hipMemsetAsync(deg, 0, N_NODES * sizeof(int), stream);
    k_deg<<<(E_EDGES + B - 1) / B, B, 0, stream>>>(ei, deg);
    k_scan1<<<NCHUNK, B, 0, stream>>>(deg, bsum);
    k_scan2<<<1, 64, 0, stream>>>(bsum, boff);
    k_scan3<<<NCHUNK, B, 0, stream>>>(deg, boff, rowptr, cursor, edat);
    k_fill<<<(E_EDGES + B - 1) / B, B, 0, stream>>>(ei, cursor, edat);
    k_prep<<<((size_t)N_NODES * 64 + B - 1) / B, B, 0, stream>>>(rowptr, edat, ea, eab);
    k_trans3<<<dim3((HC * IN_CH + B - 1) / B, 3), B, 0, stream>>>(Wl, Wr, We, WlT, WrT, WeT);
    k_gemm2<<<dim3((N_NODES + 63) / 64, 4), B, 0, stream>>>(x, WlT, WrT, xlb, xrb, N_NODES);
    k_fused<<<(M_TOT + 63) / 64, 512, 0, stream>>>(edat, rowptr, eab, WeT,
                                                   xlb, xrb, att, bias, logits, out);
    k_cleanup<<<((size_t)N_NODES * 64 + B - 1) / B, B, 0, stream>>>(rowptr, edat, logits,
                                                                    xlb, bias, out);
}

// Round 12
// 221.142 us; speedup vs baseline: 1.3088x; 1.0514x over previous
//
#include <hip/hip_runtime.h>

#define N_NODES 20000
#define E_EDGES 160000
#define IN_CH 128
#define H_HEADS 8
#define C_CH 64
#define HC 512
#define M_TOT (E_EDGES + N_NODES)
#define NEG_SLOPE 0.2f
#define NCHUNK ((N_NODES + 255) / 256)

typedef __attribute__((ext_vector_type(8))) short bf16x8;
typedef __attribute__((ext_vector_type(4))) float f32x4;

__device__ __forceinline__ unsigned short f2bf(float f) {
    unsigned u = __float_as_uint(f);
    unsigned r = (u + 0x7FFFu + ((u >> 16) & 1u)) >> 16;   // RNE
    return (unsigned short)r;
}
__device__ __forceinline__ unsigned short f2bf_trunc(float f) {
    return (unsigned short)(__float_as_uint(f) >> 16);     // 1-inst truncate (xeT only)
}
__device__ __forceinline__ float bf2f(unsigned short s) {
    return __uint_as_float((unsigned)s << 16);
}
__device__ __forceinline__ float bfx(const bf16x8& v0, const bf16x8& v1, int idx) {
    return bf2f((unsigned short)((idx < 8) ? v0[idx] : v1[idx - 8]));
}
__device__ __forceinline__ void agg8(float* ac, const bf16x8& v, float alpha) {
    #pragma unroll
    for (int jj = 0; jj < 8; ++jj) ac[jj] = fmaf(alpha, bf2f((unsigned short)v[jj]), ac[jj]);
}

#define GLOAD_LDS16(gsrc, ldst) \
    __builtin_amdgcn_global_load_lds((const __attribute__((address_space(1))) void*)(gsrc), \
                                     (__attribute__((address_space(3))) void*)(ldst), 16, 0, 0)

// ---------------- CSR build ----------------
__global__ void k_deg(const int* __restrict__ ei, int* __restrict__ deg) {
    int e = blockIdx.x * blockDim.x + threadIdx.x;
    if (e >= E_EDGES) return;
    atomicAdd(&deg[ei[E_EDGES + e]], 1);
}

__global__ void k_scan1(const int* __restrict__ deg, int* __restrict__ bsum) {
    __shared__ int red[256];
    int tid = threadIdx.x;
    int i = blockIdx.x * 256 + tid;
    red[tid] = (i < N_NODES) ? deg[i] + 1 : 0;
    __syncthreads();
    for (int off = 128; off > 0; off >>= 1) {
        if (tid < off) red[tid] += red[tid + off];
        __syncthreads();
    }
    if (tid == 0) bsum[blockIdx.x] = red[0];
}

__global__ void k_scan2(const int* __restrict__ bsum, int* __restrict__ boff) {
    if (threadIdx.x == 0) {
        int run = 0;
        for (int b = 0; b < NCHUNK; ++b) { boff[b] = run; run += bsum[b]; }
    }
}

__global__ void k_scan3(const int* __restrict__ deg, const int* __restrict__ boff,
                        int* __restrict__ rowptr, int* __restrict__ cursor,
                        int4* __restrict__ edat) {
    __shared__ int buf[256];
    int tid = threadIdx.x;
    int i = blockIdx.x * 256 + tid;
    int v = (i < N_NODES) ? deg[i] + 1 : 0;
    buf[tid] = v;
    __syncthreads();
    for (int off = 1; off < 256; off <<= 1) {
        int tv = (tid >= off) ? buf[tid - off] : 0;
        __syncthreads();
        buf[tid] += tv;
        __syncthreads();
    }
    if (i < N_NODES) {
        int excl = boff[blockIdx.x] + buf[tid] - v;
        rowptr[i] = excl;
        edat[excl] = make_int4(E_EDGES + i, i, i, 0);   // self-loop in slot 0
        cursor[i] = excl + 1;
        if (i == N_NODES - 1) rowptr[N_NODES] = excl + v;   // == M_TOT
    }
}

__global__ void k_fill(const int* __restrict__ ei, int* __restrict__ cursor,
                       int4* __restrict__ edat) {
    int e = blockIdx.x * blockDim.x + threadIdx.x;
    if (e >= E_EDGES) return;
    int d = ei[E_EDGES + e];
    int slot = atomicAdd(&cursor[d], 1);
    edat[slot] = make_int4(e, ei[e], d, 0);
}

// ---------------- k_prep: eab[p][128] bf16 in CSR order + self-loop mean (4-deep) ----------------
__global__ void k_prep(const int* __restrict__ rowptr, const int4* __restrict__ edat,
                       const float* __restrict__ ea, unsigned short* __restrict__ eab) {
    int node = (blockIdx.x * blockDim.x + threadIdx.x) >> 6;
    int lane = threadIdx.x & 63;
    if (node >= N_NODES) return;
    int beg = rowptr[node] + 1, end = rowptr[node + 1];
    int len = end - beg;
    float s0 = 0.f, s1 = 0.f;
    float a0 = 0, b0 = 0, a1 = 0, b1 = 0, a2 = 0, b2 = 0, a3 = 0, b3 = 0;
    const float* P;
    if (0 < len) { P = ea + (size_t)edat[beg + 0].x * 128 + lane; a0 = P[0]; b0 = P[64]; }
    if (1 < len) { P = ea + (size_t)edat[beg + 1].x * 128 + lane; a1 = P[0]; b1 = P[64]; }
    if (2 < len) { P = ea + (size_t)edat[beg + 2].x * 128 + lane; a2 = P[0]; b2 = P[64]; }
    if (3 < len) { P = ea + (size_t)edat[beg + 3].x * 128 + lane; a3 = P[0]; b3 = P[64]; }
    int j = 0;
    #define PREP_STEP(A, B) { \
        s0 += A; s1 += B; \
        eab[(size_t)(beg + j) * 128 + lane] = f2bf(A); \
        eab[(size_t)(beg + j) * 128 + 64 + lane] = f2bf(B); \
        if (j + 4 < len) { P = ea + (size_t)edat[beg + j + 4].x * 128 + lane; A = P[0]; B = P[64]; } \
        ++j; }
    for (; j + 4 <= len; ) {
        PREP_STEP(a0, b0);
        PREP_STEP(a1, b1);
        PREP_STEP(a2, b2);
        PREP_STEP(a3, b3);
    }
    if (j < len) { s0 += a0; s1 += b0; eab[(size_t)(beg + j) * 128 + lane] = f2bf(a0); eab[(size_t)(beg + j) * 128 + 64 + lane] = f2bf(b0); ++j; }
    if (j < len) { s0 += a1; s1 += b1; eab[(size_t)(beg + j) * 128 + lane] = f2bf(a1); eab[(size_t)(beg + j) * 128 + 64 + lane] = f2bf(b1); ++j; }
    if (j < len) { s0 += a2; s1 += b2; eab[(size_t)(beg + j) * 128 + lane] = f2bf(a2); eab[(size_t)(beg + j) * 128 + 64 + lane] = f2bf(b2); ++j; }
    #undef PREP_STEP
    float inv = 1.f / fmaxf((float)len, 1.f);
    eab[(size_t)(beg - 1) * 128 + lane] = f2bf(s0 * inv);
    eab[(size_t)(beg - 1) * 128 + 64 + lane] = f2bf(s1 * inv);
}

// ---------------- weight transpose + bf16 (all three) ----------------
__global__ void k_trans3(const float* __restrict__ Wl, const float* __restrict__ Wr,
                         const float* __restrict__ We,
                         unsigned short* __restrict__ WlT, unsigned short* __restrict__ WrT,
                         unsigned short* __restrict__ WeT) {
    int idx = blockIdx.x * blockDim.x + threadIdx.x;
    if (idx >= HC * IN_CH) return;
    int m = blockIdx.y;
    const float* W = (m == 0) ? Wl : (m == 1) ? Wr : We;
    unsigned short* WT = (m == 0) ? WlT : (m == 1) ? WrT : WeT;
    int n = idx >> 7, k = idx & 127;
    WT[idx] = f2bf(W[(size_t)k * HC + n]);
}

// ---------------- merged dual MFMA GEMM ----------------
__global__ void k_gemm2(const float* __restrict__ A,
                        const unsigned short* __restrict__ WlT,
                        const unsigned short* __restrict__ WrT,
                        unsigned short* __restrict__ xlb, unsigned short* __restrict__ xrb,
                        int M) {
    __shared__ short As[64 * 128];
    int row0 = blockIdx.x * 64;
    int sel = blockIdx.y >> 1;
    const unsigned short* BT = sel ? WrT : WlT;
    unsigned short* Cb = sel ? xrb : xlb;
    int t = threadIdx.x;
    {
        int row = t >> 2, c0 = (t & 3) * 32;
        int gr = row0 + row;
        int sw = (row & 7) << 4;
        const float* src = A + (size_t)gr * 128 + c0;
        #pragma unroll
        for (int i = 0; i < 4; ++i) {
            bf16x8 v;
            if (gr < M) {
                const float4* p = (const float4*)(src + i * 8);
                float4 f0 = p[0], f1 = p[1];
                v[0] = f2bf(f0.x); v[1] = f2bf(f0.y); v[2] = f2bf(f0.z); v[3] = f2bf(f0.w);
                v[4] = f2bf(f1.x); v[5] = f2bf(f1.y); v[6] = f2bf(f1.z); v[7] = f2bf(f1.w);
            } else {
                #pragma unroll
                for (int j = 0; j < 8; ++j) v[j] = 0;
            }
            int off = row * 256 + (((c0 + i * 8) * 2) ^ sw);
            *(bf16x8*)((char*)As + off) = v;
        }
    }
    __syncthreads();

    int w = t >> 6, l = t & 63;
    int lr = l & 15, lk = l >> 4;
    int col0 = (blockIdx.y & 1) * 256 + w * 64;

    f32x4 acc[4][4];
    #pragma unroll
    for (int mi = 0; mi < 4; ++mi)
        #pragma unroll
        for (int fj = 0; fj < 4; ++fj)
            #pragma unroll
            for (int q = 0; q < 4; ++q) acc[mi][fj][q] = 0.f;

    #pragma unroll
    for (int k0 = 0; k0 < 4; ++k0) {
        bf16x8 a4[4];
        #pragma unroll
        for (int mi = 0; mi < 4; ++mi) {
            int row = mi * 16 + lr;
            int off = row * 256 + ((k0 * 64 + lk * 16) ^ ((row & 7) << 4));
            a4[mi] = *(const bf16x8*)((const char*)As + off);
        }
        #pragma unroll
        for (int fj = 0; fj < 4; ++fj) {
            bf16x8 b = *(const bf16x8*)(BT + (size_t)(col0 + fj * 16 + lr) * 128 + k0 * 32 + lk * 8);
            #pragma unroll
            for (int mi = 0; mi < 4; ++mi)
                acc[mi][fj] = __builtin_amdgcn_mfma_f32_16x16x32_bf16(a4[mi], b, acc[mi][fj], 0, 0, 0);
        }
    }
    #pragma unroll
    for (int mi = 0; mi < 4; ++mi) {
        #pragma unroll
        for (int reg = 0; reg < 4; ++reg) {
            int r = row0 + mi * 16 + lk * 4 + reg;
            if (r < M) {
                unsigned short* cp = Cb + (size_t)r * 512 + col0 + lr;
                #pragma unroll
                for (int fj = 0; fj < 4; ++fj) cp[fj * 16] = f2bf(acc[mi][fj][reg]);
            }
        }
    }
}

// ---------------- fused: 8-wave block, one head per wave, eab staged ONCE ----------------
#define PREF(R, CB, SLOT) { \
    int s_ = s_src[R], d_ = s_dst[R]; \
    const bf16x8* xp_ = (const bf16x8*)(xlb + (size_t)s_ * 512 + (CB) + q * 16); \
    pa0[SLOT] = xp_[0]; pa1[SLOT] = xp_[1]; \
    const bf16x8* rp_ = (const bf16x8*)(xrb + (size_t)d_ * 512 + (CB) + q * 16); \
    pb0[SLOT] = rp_[0]; pb1[SLOT] = rp_[1]; }

__global__ __launch_bounds__(512, 2)
void k_fused(const int4* __restrict__ edat, const int* __restrict__ rowptr,
             const unsigned short* __restrict__ eab,
             const unsigned short* __restrict__ WeT,
             const unsigned short* __restrict__ xlb,
             const unsigned short* __restrict__ xrb,
             const float* __restrict__ att, const float* __restrict__ bias,
             float* __restrict__ logits, float* __restrict__ out) {
    __shared__ short As[64 * 128];
    __shared__ unsigned short xeT[8][16][72];   // bf16, 144B row stride
    __shared__ float att_s[512];
    __shared__ float lg[64][8];
    __shared__ int s_src[64], s_dst[64];
    __shared__ int own_node[64], own_beg[64], own_len[64];
    __shared__ int n_own;
    int row0 = blockIdx.x * 64;
    int t = threadIdx.x;

    if (t == 0) n_own = 0;
    __syncthreads();

    // async staged A-tile (once): contiguous bf16 rows of eab, inverse-swizzled source
    {
        int l = t & 63;
        int c_base = (t >> 6) * 2;
        #pragma unroll
        for (int i = 0; i < 2; ++i) {
            int c = c_base + i;
            int row_local = c * 4 + (l >> 4);
            int grow = row0 + row_local;
            if (grow > M_TOT - 1) grow = M_TOT - 1;
            int chunk = (l & 15) ^ (row_local & 7);
            const char* src = (const char*)eab + (size_t)grow * 256 + chunk * 16;
            char* dst = (char*)As + c * 1024;
            GLOAD_LDS16(src, dst);
        }
    }

    if (t < 64) {
        int p = row0 + t;
        int s = 0, d = 0;
        if (p < M_TOT) {
            int4 v = edat[p];
            s = v.y; d = v.z;
            int pb = rowptr[d], pe = rowptr[d + 1];
            if (pb == p && pe <= row0 + 64) {          // interior segment, first row
                int idx = atomicAdd(&n_own, 1);
                own_node[idx] = d; own_beg[idx] = t; own_len[idx] = pe - pb;
            }
        }
        s_src[t] = s; s_dst[t] = d;
    }
    att_s[t] = att[t];

    asm volatile("s_waitcnt vmcnt(0)");
    __syncthreads();

    int w = t >> 6, l = t & 63;          // w = head (0..7)
    int lr = l & 15, lk = l >> 4;
    int eloc = l >> 2, q = l & 3;        // epilogue: 4 lanes per edge
    int cb = w * 64;

    bf16x8 pa0[2], pa1[2], pb0[2], pb1[2];
    f32x4 acc[4][4];

    PREF(eloc, cb, 0);

    #pragma unroll
    for (int mi = 0; mi < 4; ++mi)
        #pragma unroll
        for (int fj = 0; fj < 4; ++fj)
            #pragma unroll
            for (int qq = 0; qq < 4; ++qq) acc[mi][fj][qq] = 0.f;

    #pragma unroll
    for (int k0 = 0; k0 < 4; ++k0) {
        bf16x8 a4[4];
        #pragma unroll
        for (int mi = 0; mi < 4; ++mi) {
            int row = mi * 16 + lr;
            int off = row * 256 + ((k0 * 64 + lk * 16) ^ ((row & 7) << 4));
            a4[mi] = *(const bf16x8*)((const char*)As + off);
        }
        #pragma unroll
        for (int fj = 0; fj < 4; ++fj) {
            bf16x8 b = *(const bf16x8*)(WeT + (size_t)(cb + fj * 16 + lr) * 128 + k0 * 32 + lk * 8);
            #pragma unroll
            for (int mi = 0; mi < 4; ++mi)
                acc[mi][fj] = __builtin_amdgcn_mfma_f32_16x16x32_bf16(a4[mi], b, acc[mi][fj], 0, 0, 0);
        }
    }

    #pragma unroll
    for (int mi = 0; mi < 4; ++mi) {
        if (mi < 3) { PREF(mi * 16 + 16 + eloc, cb, (mi + 1) & 1); }

        #pragma unroll
        for (int fj = 0; fj < 4; ++fj)
            #pragma unroll
            for (int reg = 0; reg < 4; ++reg)
                xeT[w][lk * 4 + reg][fj * 16 + lr] = f2bf_trunc(acc[mi][fj][reg]);

        const bf16x8 ca0 = pa0[mi & 1], ca1 = pa1[mi & 1];
        const bf16x8 cb0v = pb0[mi & 1], cb1v = pb1[mi & 1];

        bf16x8 x0 = *(const bf16x8*)&xeT[w][eloc][q * 16];
        bf16x8 x1 = *(const bf16x8*)&xeT[w][eloc][q * 16 + 8];

        float sum = 0.f;
        #pragma unroll
        for (int sg = 0; sg < 4; ++sg) {
            float4 av = *(const float4*)&att_s[cb + q * 16 + sg * 4];
            float v0 = bfx(x0, x1, sg * 4 + 0) + bfx(ca0, ca1, sg * 4 + 0) + bfx(cb0v, cb1v, sg * 4 + 0);
            float v1 = bfx(x0, x1, sg * 4 + 1) + bfx(ca0, ca1, sg * 4 + 1) + bfx(cb0v, cb1v, sg * 4 + 1);
            float v2 = bfx(x0, x1, sg * 4 + 2) + bfx(ca0, ca1, sg * 4 + 2) + bfx(cb0v, cb1v, sg * 4 + 2);
            float v3 = bfx(x0, x1, sg * 4 + 3) + bfx(ca0, ca1, sg * 4 + 3) + bfx(cb0v, cb1v, sg * 4 + 3);
            v0 = (v0 > 0.f) ? v0 : v0 * NEG_SLOPE;
            v1 = (v1 > 0.f) ? v1 : v1 * NEG_SLOPE;
            v2 = (v2 > 0.f) ? v2 : v2 * NEG_SLOPE;
            v3 = (v3 > 0.f) ? v3 : v3 * NEG_SLOPE;
            sum = fmaf(av.x, v0, sum);
            sum = fmaf(av.y, v1, sum);
            sum = fmaf(av.z, v2, sum);
            sum = fmaf(av.w, v3, sum);
        }
        sum += __shfl_xor(sum, 1, 64);
        sum += __shfl_xor(sum, 2, 64);
        if (q == 0) lg[mi * 16 + eloc][w] = sum;
    }
    __syncthreads();

    // coalesced logits write: 64 rows x 8 heads contiguous
    {
        int nval = (M_TOT - row0 < 64 ? M_TOT - row0 : 64) * 8;
        if (t < 256 && t * 2 < nval) {
            const float* lf = (const float*)lg;
            float2 v = { lf[t * 2], lf[t * 2 + 1] };
            *(float2*)(logits + (size_t)row0 * 8 + t * 2) = v;
        }
    }

    // interior softmax + aggregation: wave w handles segments w, w+8, ... (4-deep prefetch)
    {
        int lane = t & 63;
        int h = lane >> 3;
        for (int o = w; o < n_own; o += 8) {
            int d = own_node[o], rb = own_beg[o], len = own_len[o];
            float m = -3.4e38f;
            for (int j = 0; j < len; ++j) m = fmaxf(m, lg[rb + j][h]);
            float den = 0.f;
            for (int j = 0; j < len; ++j) den += __expf(lg[rb + j][h] - m);
            float rden = 1.f / den;
            float ac[8] = {};
            bf16x8 v0 = {}, v1 = {}, v2 = {}, v3 = {};
            if (0 < len) v0 = *(const bf16x8*)(xlb + (size_t)s_src[rb + 0] * 512 + lane * 8);
            if (1 < len) v1 = *(const bf16x8*)(xlb + (size_t)s_src[rb + 1] * 512 + lane * 8);
            if (2 < len) v2 = *(const bf16x8*)(xlb + (size_t)s_src[rb + 2] * 512 + lane * 8);
            if (3 < len) v3 = *(const bf16x8*)(xlb + (size_t)s_src[rb + 3] * 512 + lane * 8);
            int j = 0;
            #define AGG_STEP(V) { \
                agg8(ac, V, __expf(lg[rb + j][h] - m) * rden); \
                if (j + 4 < len) V = *(const bf16x8*)(xlb + (size_t)s_src[rb + j + 4] * 512 + lane * 8); \
                ++j; }
            for (; j + 4 <= len; ) {
                AGG_STEP(v0);
                AGG_STEP(v1);
                AGG_STEP(v2);
                AGG_STEP(v3);
            }
            if (j < len) { agg8(ac, v0, __expf(lg[rb + j][h] - m) * rden); ++j; }
            if (j < len) { agg8(ac, v1, __expf(lg[rb + j][h] - m) * rden); ++j; }
            if (j < len) { agg8(ac, v2, __expf(lg[rb + j][h] - m) * rden); ++j; }
            #undef AGG_STEP
            float4* op = (float4*)(out + (size_t)d * 512 + lane * 8);
            const float4* bp = (const float4*)(bias + lane * 8);
            float4 bv0 = bp[0], bv1 = bp[1];
            float4 r0 = { ac[0] + bv0.x, ac[1] + bv0.y, ac[2] + bv0.z, ac[3] + bv0.w };
            float4 r1 = { ac[4] + bv1.x, ac[5] + bv1.y, ac[6] + bv1.z, ac[7] + bv1.w };
            op[0] = r0; op[1] = r1;
        }
    }
}

// ---------------- cleanup: boundary segments only (4-deep prefetch) ----------------
__global__ void k_cleanup(const int* __restrict__ rowptr, const int4* __restrict__ edat,
                          const float* __restrict__ logits,
                          const unsigned short* __restrict__ xlb, const float* __restrict__ bias,
                          float* __restrict__ out) {
    int node = (blockIdx.x * blockDim.x + threadIdx.x) >> 6;
    int lane = threadIdx.x & 63;
    if (node >= N_NODES) return;
    int beg = rowptr[node], end = rowptr[node + 1];
    if ((beg >> 6) == ((end - 1) >> 6)) return;   // interior: handled in k_fused
    int h = lane >> 3;
    int len = end - beg;

    float m = -3.4e38f;
    for (int p = beg; p < end; ++p) m = fmaxf(m, logits[(size_t)p * 8 + h]);
    float den = 0.f;
    for (int p = beg; p < end; ++p) den += __expf(logits[(size_t)p * 8 + h] - m);
    float rden = 1.f / den;

    float acc[8] = {};
    bf16x8 v0 = {}, v1 = {}, v2 = {}, v3 = {};
    if (0 < len) v0 = *(const bf16x8*)(xlb + (size_t)edat[beg + 0].y * 512 + lane * 8);
    if (1 < len) v1 = *(const bf16x8*)(xlb + (size_t)edat[beg + 1].y * 512 + lane * 8);
    if (2 < len) v2 = *(const bf16x8*)(xlb + (size_t)edat[beg + 2].y * 512 + lane * 8);
    if (3 < len) v3 = *(const bf16x8*)(xlb + (size_t)edat[beg + 3].y * 512 + lane * 8);
    int j = 0;
    #define CLN_STEP(V) { \
        agg8(acc, V, __expf(logits[(size_t)(beg + j) * 8 + h] - m) * rden); \
        if (j + 4 < len) V = *(const bf16x8*)(xlb + (size_t)edat[beg + j + 4].y * 512 + lane * 8); \
        ++j; }
    for (; j + 4 <= len; ) {
        CLN_STEP(v0);
        CLN_STEP(v1);
        CLN_STEP(v2);
        CLN_STEP(v3);
    }
    if (j < len) { agg8(acc, v0, __expf(logits[(size_t)(beg + j) * 8 + h] - m) * rden); ++j; }
    if (j < len) { agg8(acc, v1, __expf(logits[(size_t)(beg + j) * 8 + h] - m) * rden); ++j; }
    if (j < len) { agg8(acc, v2, __expf(logits[(size_t)(beg + j) * 8 + h] - m) * rden); ++j; }
    #undef CLN_STEP
    float4* op = (float4*)(out + (size_t)node * 512 + lane * 8);
    const float4* bp = (const float4*)(bias + lane * 8);
    float4 bv0 = bp[0], bv1 = bp[1];
    float4 r0 = { acc[0] + bv0.x, acc[1] + bv0.y, acc[2] + bv0.z, acc[3] + bv0.w };
    float4 r1 = { acc[4] + bv1.x, acc[5] + bv1.y, acc[6] + bv1.z, acc[7] + bv1.w };
    op[0] = r0; op[1] = r1;
}

extern "C" void kernel_launch(void* const* d_in, const int* in_sizes, int n_in,
                              void* d_out, int out_size, void* d_ws, size_t ws_size,
                              hipStream_t stream) {
    const float* x    = (const float*)d_in[0];
    const int*   ei   = (const int*)d_in[1];
    const float* ea   = (const float*)d_in[2];
    const float* Wl   = (const float*)d_in[3];
    const float* Wr   = (const float*)d_in[4];
    const float* We   = (const float*)d_in[5];
    const float* att  = (const float*)d_in[6];
    const float* bias = (const float*)d_in[7];
    float* out = (float*)d_out;

    unsigned short* xlb = (unsigned short*)d_ws;             // N*512 bf16
    unsigned short* xrb = xlb + (size_t)N_NODES * HC;        // N*512 bf16
    unsigned short* WlT = xrb + (size_t)N_NODES * HC;        // 512*128 bf16
    unsigned short* WrT = WlT + HC * IN_CH;
    unsigned short* WeT = WrT + HC * IN_CH;
    unsigned short* eab = WeT + HC * IN_CH;                  // M_TOT*128 bf16
    float* logits    = (float*)(eab + (size_t)M_TOT * IN_CH); // M_TOT*8 f32
    int4* edat       = (int4*)(logits + (size_t)M_TOT * 8);  // M_TOT int4
    int* deg         = (int*)(edat + M_TOT);
    int* rowptr      = deg + N_NODES;
    int* cursor      = rowptr + N_NODES + 1;
    int* bsum        = cursor + N_NODES;
    int* boff        = bsum + NCHUNK;

    const int B = 256;
    hipMemsetAsync(deg, 0, N_NODES * sizeof(int), stream);
    k_deg<<<(E_EDGES + B - 1) / B, B, 0, stream>>>(ei, deg);
    k_scan1<<<NCHUNK, B, 0, stream>>>(deg, bsum);
    k_scan2<<<1, 64, 0, stream>>>(bsum, boff);
    k_scan3<<<NCHUNK, B, 0, stream>>>(deg, boff, rowptr, cursor, edat);
    k_fill<<<(E_EDGES + B - 1) / B, B, 0, stream>>>(ei, cursor, edat);
    k_prep<<<((size_t)N_NODES * 64 + B - 1) / B, B, 0, stream>>>(rowptr, edat, ea, eab);
    k_trans3<<<dim3((HC * IN_CH + B - 1) / B, 3), B, 0, stream>>>(Wl, Wr, We, WlT, WrT, WeT);
    k_gemm2<<<dim3((N_NODES + 63) / 64, 4), B, 0, stream>>>(x, WlT, WrT, xlb, xrb, N_NODES);
    k_fused<<<(M_TOT + 63) / 64, 512, 0, stream>>>(edat, rowptr, eab, WeT,
                                                   xlb, xrb, att, bias, logits, out);
    k_cleanup<<<((size_t)N_NODES * 64 + B - 1) / B, B, 0, stream>>>(rowptr, edat, logits,
                                                                    xlb, bias, out);
}